// Round 9
// baseline (247.723 us; speedup 1.0000x reference)
//
#include <hip/hip_runtime.h>

#define N_RET  200000
#define N_ORIG 100000
#define N_EDGE 800000
#define NB_RET  ((N_RET  + 511) >> 9)   // 391 buckets of 512 nodes
#define NB_ORIG ((N_ORIG + 511) >> 9)   // 196
#define NBIN    ((N_EDGE + 8191) / 8192) // 98 edge-chunk blocks
#define NBLK_HO ((N_ORIG + 63) / 64)    // 1563
#define NBLK_XR ((N_RET + 63) / 64)     // 3125

typedef __attribute__((ext_vector_type(8))) short bf16x8;   // 8 bf16 (4 VGPRs)
typedef __attribute__((ext_vector_type(4))) float f32x4;    // MFMA C/D

__device__ __forceinline__ ushort f2bf(float f) {
    union { float f; unsigned u; } v; v.f = f;
    unsigned r = v.u + 0x7FFFu + ((v.u >> 16) & 1u);   // RNE
    return (ushort)(r >> 16);
}
__device__ __forceinline__ float bf2f(ushort u) {
    union { unsigned u; float f; } v; v.u = ((unsigned)u) << 16;
    return v.f;
}
__device__ __forceinline__ int swz(int byteoff) {   // XOR swizzle for LDS tiles
    return byteoff ^ ((byteoff >> 4) & 0x70);
}

// ---------------- prep: all 4 weight transposes (bf16) + zero bucket counters ----------------
__global__ void prep_kernel(const float* __restrict__ Wl1, const float* __restrict__ Wr1,
                            const float* __restrict__ Wg2, const float* __restrict__ Wout,
                            ushort* __restrict__ wtl1, ushort* __restrict__ wtr1,
                            ushort* __restrict__ wtg2, ushort* __restrict__ wto,
                            int* __restrict__ bcnt) {
    const int b = blockIdx.x, t = threadIdx.x;
    if (b == 224) {
        for (int i = t; i < 1024; i += 256) bcnt[i] = 0;
        return;
    }
    const float* W; ushort* WT; int base, nshift;
    if (b < 64)       { W = Wl1;  WT = wtl1; base = b;       nshift = 7; }
    else if (b < 128) { W = Wr1;  WT = wtr1; base = b - 64;  nshift = 7; }
    else if (b < 192) { W = Wg2;  WT = wtg2; base = b - 128; nshift = 7; }
    else              { W = Wout; WT = wto;  base = b - 192; nshift = 6; }
    int i = base * 256 + t;
    int k = i >> nshift, n = i & ((1 << nshift) - 1);
    WT[n * 128 + k] = f2bf(W[i]);   // K = 128 for all
}

// ---------------- bucket-level histogram (both directions in one pass) ----------------
__global__ __launch_bounds__(256) void bucket_count(const int* __restrict__ ridx,
                                                    const int* __restrict__ cidx,
                                                    int* __restrict__ bcnt1,
                                                    int* __restrict__ bcnt2) {
    __shared__ int h1[512], h2[512];
    const int t = threadIdx.x;
    const int c0 = blockIdx.x * 8192;
    for (int i = t; i < 512; i += 256) { h1[i] = 0; h2[i] = 0; }
    __syncthreads();
    for (int i = t; i < 8192; i += 256) {
        int e = c0 + i;
        if (e < N_EDGE) {
            atomicAdd(&h1[ridx[e] >> 9], 1);
            atomicAdd(&h2[cidx[e] >> 9], 1);
        }
    }
    __syncthreads();
    for (int b = t; b < NB_RET; b += 256)
        if (h1[b]) atomicAdd(&bcnt1[b], h1[b]);
    for (int b = t; b < NB_ORIG; b += 256)
        if (h2[b]) atomicAdd(&bcnt2[b], h2[b]);
}

// ---------------- single-block scan of bucket counts -> bucket offsets + cursors ----------------
__global__ __launch_bounds__(256) void scan_buckets(const int* __restrict__ bcnt1,
                                                    int* __restrict__ boff1, int* __restrict__ bcur1,
                                                    const int* __restrict__ bcnt2,
                                                    int* __restrict__ boff2, int* __restrict__ bcur2,
                                                    int* __restrict__ off_ret,
                                                    int* __restrict__ off_orig) {
    __shared__ int sm[256];
    const int t = threadIdx.x;
    {
        int a0 = (2 * t     < NB_RET) ? bcnt1[2 * t]     : 0;
        int a1 = (2 * t + 1 < NB_RET) ? bcnt1[2 * t + 1] : 0;
        sm[t] = a0 + a1;
        __syncthreads();
        for (int d = 1; d < 256; d <<= 1) {
            int v = (t >= d) ? sm[t - d] : 0;
            __syncthreads(); sm[t] += v; __syncthreads();
        }
        int tb = t ? sm[t - 1] : 0;
        if (2 * t < NB_RET)     { boff1[2 * t]     = tb;      bcur1[2 * t]     = tb; }
        if (2 * t + 1 < NB_RET) { boff1[2 * t + 1] = tb + a0; bcur1[2 * t + 1] = tb + a0; }
        if (t == 0) { boff1[NB_RET] = N_EDGE; off_ret[N_RET] = N_EDGE; }
        __syncthreads();
    }
    {
        int a0 = (2 * t     < NB_ORIG) ? bcnt2[2 * t]     : 0;
        int a1 = (2 * t + 1 < NB_ORIG) ? bcnt2[2 * t + 1] : 0;
        sm[t] = a0 + a1;
        __syncthreads();
        for (int d = 1; d < 256; d <<= 1) {
            int v = (t >= d) ? sm[t - d] : 0;
            __syncthreads(); sm[t] += v; __syncthreads();
        }
        int tb = t ? sm[t - 1] : 0;
        if (2 * t < NB_ORIG)     { boff2[2 * t]     = tb;      bcur2[2 * t]     = tb; }
        if (2 * t + 1 < NB_ORIG) { boff2[2 * t + 1] = tb + a0; bcur2[2 * t + 1] = tb + a0; }
        if (t == 0) { boff2[NB_ORIG] = N_EDGE; off_orig[N_ORIG] = N_EDGE; }
    }
}

// ---------------- pass A (both dirs): bin edges by dst bucket; record (local_dst<<18)|src ----------------
__global__ __launch_bounds__(256) void bin_both(const int* __restrict__ ridx,
                                                const int* __restrict__ cidx,
                                                int* __restrict__ bcur1, int* __restrict__ bcur2,
                                                int* __restrict__ binned1, int* __restrict__ binned2) {
    __shared__ int hist[512], base[512], lcur[512];
    const int t = threadIdx.x;
    const bool second = blockIdx.x >= NBIN;
    const int* dst = second ? cidx : ridx;
    const int* src = second ? ridx : cidx;
    int* bcur = second ? bcur2 : bcur1;
    int* binned = second ? binned2 : binned1;
    const int nbuckets = second ? NB_ORIG : NB_RET;
    const int c0 = (second ? blockIdx.x - NBIN : blockIdx.x) * 8192;
    for (int i = t; i < 512; i += 256) { hist[i] = 0; lcur[i] = 0; }
    __syncthreads();
    for (int i = t; i < 8192; i += 256) {
        int e = c0 + i;
        if (e < N_EDGE) atomicAdd(&hist[dst[e] >> 9], 1);
    }
    __syncthreads();
    for (int b = t; b < nbuckets; b += 256)
        base[b] = hist[b] > 0 ? atomicAdd(&bcur[b], hist[b]) : 0;
    __syncthreads();
    for (int i = t; i < 8192; i += 256) {
        int e = c0 + i;
        if (e < N_EDGE) {
            int d = dst[e];
            int b = d >> 9;
            int r = atomicAdd(&lcur[b], 1);
            binned[base[b] + r] = ((d & 511) << 18) | src[e];
        }
    }
}

// ---------------- pass B (both dirs): per-bucket node-offset build + CSR fill ----------------
__global__ __launch_bounds__(256) void fill_both(const int* __restrict__ binned1,
                                                 const int* __restrict__ boff1,
                                                 int* __restrict__ off_ret, int* __restrict__ el1,
                                                 const int* __restrict__ binned2,
                                                 const int* __restrict__ boff2,
                                                 int* __restrict__ off_orig, int* __restrict__ el2) {
    __shared__ int hist[512];
    __shared__ int sm[256];
    const int t = threadIdx.x;
    const bool second = blockIdx.x >= NB_RET;
    const int bkt = second ? blockIdx.x - NB_RET : blockIdx.x;
    const int* binned = second ? binned2 : binned1;
    const int* boff = second ? boff2 : boff1;
    int* off = second ? off_orig : off_ret;
    int* el  = second ? el2 : el1;
    const int nnodes = second ? N_ORIG : N_RET;
    const int base = bkt << 9;
    const int nvalid = min(512, nnodes - base);
    const int s0 = boff[bkt], s1 = boff[bkt + 1];
    for (int i = t; i < 512; i += 256) hist[i] = 0;
    __syncthreads();
    for (int i = s0 + t; i < s1; i += 256)
        atomicAdd(&hist[binned[i] >> 18], 1);
    __syncthreads();
    int a0 = hist[2 * t], a1 = hist[2 * t + 1];
    sm[t] = a0 + a1;
    __syncthreads();
    for (int d = 1; d < 256; d <<= 1) {
        int v = (t >= d) ? sm[t - d] : 0;
        __syncthreads(); sm[t] += v; __syncthreads();
    }
    int tb = (t ? sm[t - 1] : 0) + s0;
    if (2 * t < nvalid)     off[base + 2 * t]     = tb;
    if (2 * t + 1 < nvalid) off[base + 2 * t + 1] = tb + a0;
    hist[2 * t] = tb;
    hist[2 * t + 1] = tb + a0;
    __syncthreads();
    for (int i = s0 + t; i < s1; i += 256) {
        int v = binned[i];
        int p = atomicAdd(&hist[v >> 18], 1);
        el[p] = v & 0x3FFFF;
    }
}

// ---------------- merged linear GEMMs v2: A direct global->reg, W^T in LDS ----------------
// ho = bf16(x_orig@Wl1), xr = bf16(x_ret@Wr1). One dispatch, 32 KB LDS, one barrier.
__global__ __launch_bounds__(256) void gemm_lin(const float* __restrict__ Ao,
                                                const float* __restrict__ Ar,
                                                const ushort* __restrict__ WTl,
                                                const ushort* __restrict__ WTr,
                                                ushort* __restrict__ hoB,
                                                ushort* __restrict__ xrB) {
    __shared__ ushort Wlds[128 * 128];   // 32 KB
    const int t = threadIdx.x;
    const bool second = blockIdx.x >= NBLK_HO;
    const float* A = second ? Ar : Ao;
    const ushort* WT = second ? WTr : WTl;
    ushort* outp = second ? xrB : hoB;
    const int M = second ? N_RET : N_ORIG;
    const int i0 = (second ? blockIdx.x - NBLK_HO : blockIdx.x) * 64;

    // stage W^T (reused by all 4 waves; A has no reuse -> stays in regs)
    #pragma unroll
    for (int it = 0; it < 8; ++it) {
        int idx = t + 256 * it;
        int n = idx >> 4, u = idx & 15;
        *(bf16x8*)&Wlds[swz(n * 256 + u * 16) >> 1] = *(const bf16x8*)&WT[idx * 8];
    }

    const int w = t >> 6, l = t & 63;
    const int r16 = l & 15, kg = l >> 4;
    const int arow = min(i0 + 16 * w + r16, M - 1);

    // A fragments: 4 x 8 f32 direct loads (wave covers 16 rows x 128B full lines per ks)
    bf16x8 a[4];
    #pragma unroll
    for (int ks = 0; ks < 4; ++ks) {
        const float* p = &A[(size_t)arow * 128 + ks * 32 + kg * 8];
        float4 v0 = *(const float4*)p;
        float4 v1 = *(const float4*)(p + 4);
        bf16x8 f;
        f[0] = (short)f2bf(v0.x); f[1] = (short)f2bf(v0.y);
        f[2] = (short)f2bf(v0.z); f[3] = (short)f2bf(v0.w);
        f[4] = (short)f2bf(v1.x); f[5] = (short)f2bf(v1.y);
        f[6] = (short)f2bf(v1.z); f[7] = (short)f2bf(v1.w);
        a[ks] = f;
    }
    __syncthreads();

    f32x4 acc[8];
    #pragma unroll
    for (int cf = 0; cf < 8; ++cf) acc[cf] = (f32x4){0.f, 0.f, 0.f, 0.f};
    #pragma unroll
    for (int cf = 0; cf < 8; ++cf) {
        int n = cf * 16 + r16;
        #pragma unroll
        for (int ks = 0; ks < 4; ++ks) {
            bf16x8 b = *(const bf16x8*)&Wlds[swz(n * 256 + kg * 16 + ks * 64) >> 1];
            acc[cf] = __builtin_amdgcn_mfma_f32_16x16x32_bf16(a[ks], b, acc[cf], 0, 0, 0);
        }
    }
    #pragma unroll
    for (int r = 0; r < 4; ++r) {
        int gr = i0 + 16 * w + 4 * kg + r;
        if (gr >= M) continue;
        #pragma unroll
        for (int cf = 0; cf < 8; ++cf)
            outp[(size_t)gr * 128 + cf * 16 + r16] = f2bf(acc[cf][r]);
    }
}

// ---------------- gather + SAGE epilogue: r1s = bf16(relu(mean_agg(ho) + xr + bl) * inv_s) ----------------
__global__ void gather_sage(const ushort* __restrict__ ho, const ushort* __restrict__ xr,
                            const int* __restrict__ off, const int* __restrict__ slist,
                            const float* __restrict__ bl, ushort* __restrict__ r1s) {
    int gt = blockIdx.x * 256 + threadIdx.x;
    int node = gt >> 4;
    if (node >= N_RET) return;
    int o8 = gt & 15;
    int s = off[node], e = off[node + 1];
    float acc[8] = {0.f, 0.f, 0.f, 0.f, 0.f, 0.f, 0.f, 0.f};
    for (int i = s; i < e; ++i) {
        int sn = slist[i];
        bf16x8 v = *(const bf16x8*)&ho[(size_t)sn * 128 + o8 * 8];
        #pragma unroll
        for (int j = 0; j < 8; ++j) acc[j] += bf2f((ushort)v[j]);
    }
    int deg = e - s;
    float rinv = 1.0f / fmaxf((float)deg, 1.0f);
    float sinv = deg > 0 ? rsqrtf((float)deg) : 0.f;
    bf16x8 xv = *(const bf16x8*)&xr[(size_t)node * 128 + o8 * 8];
    bf16x8 ov;
    #pragma unroll
    for (int j = 0; j < 8; ++j) {
        float v = fmaxf(acc[j] * rinv + bf2f((ushort)xv[j]) + bl[o8 * 8 + j], 0.f) * sinv;
        ov[j] = (short)f2bf(v);
    }
    *(bf16x8*)&r1s[(size_t)node * 128 + o8 * 8] = ov;
}

// ---------------- gather sum: g = bf16(sum of r1s rows) ----------------
__global__ void gather_sum(const ushort* __restrict__ src,
                           const int* __restrict__ off, const int* __restrict__ slist,
                           ushort* __restrict__ dst) {
    int gt = blockIdx.x * 256 + threadIdx.x;
    int node = gt >> 4;
    if (node >= N_ORIG) return;
    int o8 = gt & 15;
    int s = off[node], e = off[node + 1];
    float acc[8] = {0.f, 0.f, 0.f, 0.f, 0.f, 0.f, 0.f, 0.f};
    for (int i = s; i < e; ++i) {
        int sn = slist[i];
        bf16x8 v = *(const bf16x8*)&src[(size_t)sn * 128 + o8 * 8];
        #pragma unroll
        for (int j = 0; j < 8; ++j) acc[j] += bf2f((ushort)v[j]);
    }
    bf16x8 ov;
    #pragma unroll
    for (int j = 0; j < 8; ++j) ov[j] = (short)f2bf(acc[j]);
    *(bf16x8*)&dst[(size_t)node * 128 + o8 * 8] = ov;
}

// ---- fused double-GEMM (NO gather): t = relu(g@Wg2*inv_d + bg2); out = t@Wout + bout ----
__global__ __launch_bounds__(256) void gemm_t_out(
    const ushort* __restrict__ g, const ushort* __restrict__ WTg,
    const ushort* __restrict__ WTo, const int* __restrict__ off,
    const float* __restrict__ bg, const float* __restrict__ bo,
    float* __restrict__ out, int M) {
    __shared__ ushort Alds[64 * 128];    // 16 KB
    __shared__ ushort Wlds[128 * 128];   // 32 KB
    const int t = threadIdx.x;
    const int i0 = blockIdx.x * 64;

    // stage Wg2^T + A (bf16 direct copy)
    #pragma unroll
    for (int it = 0; it < 8; ++it) {
        int idx = t + 256 * it;
        int n = idx >> 4, u = idx & 15;
        *(bf16x8*)&Wlds[swz(n * 256 + u * 16) >> 1] = *(const bf16x8*)&WTg[idx * 8];
    }
    #pragma unroll
    for (int it = 0; it < 4; ++it) {
        int idx = t + 256 * it;
        int row = idx >> 4, u = idx & 15;
        int gr = min(i0 + row, M - 1);
        bf16x8 v = *(const bf16x8*)&g[(size_t)gr * 128 + u * 8];
        *(bf16x8*)&Alds[swz(row * 256 + u * 16) >> 1] = v;
    }
    __syncthreads();

    const int w = t >> 6, l = t & 63;
    const int r16 = l & 15, kg = l >> 4;
    const int arow = 16 * w + r16;

    bf16x8 a[4];
    #pragma unroll
    for (int ks = 0; ks < 4; ++ks)
        a[ks] = *(const bf16x8*)&Alds[swz(arow * 256 + kg * 16 + ks * 64) >> 1];
    f32x4 acc[8];
    #pragma unroll
    for (int cf = 0; cf < 8; ++cf) acc[cf] = (f32x4){0.f, 0.f, 0.f, 0.f};
    #pragma unroll
    for (int cf = 0; cf < 8; ++cf) {
        int n = cf * 16 + r16;
        #pragma unroll
        for (int ks = 0; ks < 4; ++ks) {
            bf16x8 b = *(const bf16x8*)&Wlds[swz(n * 256 + kg * 16 + ks * 64) >> 1];
            acc[cf] = __builtin_amdgcn_mfma_f32_16x16x32_bf16(a[ks], b, acc[cf], 0, 0, 0);
        }
    }
    __syncthreads();   // Alds a-frags in regs, Wlds consumed -> both reusable

    // t-tile = relu(acc*inv_d + bg) -> Alds (bf16, swizzled); stage Wout^T -> Wlds
    #pragma unroll
    for (int r = 0; r < 4; ++r) {
        int row = 16 * w + 4 * kg + r;
        int grc = min(i0 + row, M - 1);
        int dg = off[grc + 1] - off[grc];
        float di = dg > 0 ? rsqrtf((float)dg) : 0.f;
        #pragma unroll
        for (int cf = 0; cf < 8; ++cf) {
            int col = cf * 16 + r16;
            float v = fmaxf(acc[cf][r] * di + bg[col], 0.f);
            Alds[swz(row * 256 + col * 2) >> 1] = f2bf(v);
        }
    }
    #pragma unroll
    for (int it = 0; it < 4; ++it) {
        int idx = t + 256 * it;
        int n = idx >> 4, u = idx & 15;
        *(bf16x8*)&Wlds[swz(n * 256 + u * 16) >> 1] = *(const bf16x8*)&WTo[idx * 8];
    }
    __syncthreads();

    bf16x8 a2[4];
    #pragma unroll
    for (int ks = 0; ks < 4; ++ks)
        a2[ks] = *(const bf16x8*)&Alds[swz(arow * 256 + kg * 16 + ks * 64) >> 1];
    f32x4 acc2[4];
    #pragma unroll
    for (int cf = 0; cf < 4; ++cf) acc2[cf] = (f32x4){0.f, 0.f, 0.f, 0.f};
    #pragma unroll
    for (int cf = 0; cf < 4; ++cf) {
        int n = cf * 16 + r16;
        #pragma unroll
        for (int ks = 0; ks < 4; ++ks) {
            bf16x8 b = *(const bf16x8*)&Wlds[swz(n * 256 + kg * 16 + ks * 64) >> 1];
            acc2[cf] = __builtin_amdgcn_mfma_f32_16x16x32_bf16(a2[ks], b, acc2[cf], 0, 0, 0);
        }
    }
    #pragma unroll
    for (int r = 0; r < 4; ++r) {
        int gr = i0 + 16 * w + 4 * kg + r;
        if (gr >= M) continue;
        #pragma unroll
        for (int cf = 0; cf < 4; ++cf) {
            int col = cf * 16 + r16;
            out[(size_t)gr * 64 + col] = acc2[cf][r] + bo[col];
        }
    }
}

extern "C" void kernel_launch(void* const* d_in, const int* in_sizes, int n_in,
                              void* d_out, int out_size, void* d_ws, size_t ws_size,
                              hipStream_t stream) {
    const float* x_ret    = (const float*)d_in[0];
    const float* x_orig   = (const float*)d_in[1];
    const int*   ret_idx  = (const int*)d_in[2];
    const int*   orig_idx = (const int*)d_in[3];
    const float* Wl1  = (const float*)d_in[6];
    const float* bl1  = (const float*)d_in[7];
    const float* Wr1  = (const float*)d_in[8];
    const float* Wg2  = (const float*)d_in[9];
    const float* bg2  = (const float*)d_in[10];
    const float* Wout = (const float*)d_in[14];
    const float* bout = (const float*)d_in[15];
    float* out = (float*)d_out;

    // workspace layout
    ushort* hoB  = (ushort*)d_ws;                       // 100k*128 bf16 (ho, later g)
    ushort* xrB  = hoB + (size_t)N_ORIG * 128;          // 200k*128 bf16
    ushort* r1sB = xrB + (size_t)N_RET * 128;           // 200k*128 bf16
    ushort* wtl1 = r1sB + (size_t)N_RET * 128;          // 16384
    ushort* wtr1 = wtl1 + 16384;                        // 16384
    ushort* wtg2 = wtr1 + 16384;                        // 16384
    ushort* wto  = wtg2 + 16384;                        // 8192
    int* off_ret  = (int*)(wto + 8192);                 // N_RET+1
    int* off_orig = off_ret + N_RET + 1;                // N_ORIG+1
    int* bcnt1    = off_orig + N_ORIG + 1;              // 512
    int* bcnt2    = bcnt1 + 512;                        // 512 (adjacent for one-pass zero)
    int* boff1    = bcnt2 + 512;                        // 512
    int* boff2    = boff1 + 512;                        // 512
    int* bcur1    = boff2 + 512;                        // 512
    int* bcur2    = bcur1 + 512;                        // 512
    int* el1      = bcur2 + 512;                        // N_EDGE (src=orig, grouped by ret)
    int* el2      = el1 + N_EDGE;                       // N_EDGE (src=ret, grouped by orig)
    int* binned1  = el2 + N_EDGE;                       // N_EDGE packed
    int* binned2  = binned1 + N_EDGE;                   // N_EDGE packed

    prep_kernel<<<225, 256, 0, stream>>>(Wl1, Wr1, Wg2, Wout, wtl1, wtr1, wtg2, wto, bcnt1);

    bucket_count<<<NBIN, 256, 0, stream>>>(ret_idx, orig_idx, bcnt1, bcnt2);
    scan_buckets<<<1, 256, 0, stream>>>(bcnt1, boff1, bcur1, bcnt2, boff2, bcur2,
                                        off_ret, off_orig);
    bin_both<<<2 * NBIN, 256, 0, stream>>>(ret_idx, orig_idx, bcur1, bcur2, binned1, binned2);
    fill_both<<<NB_RET + NB_ORIG, 256, 0, stream>>>(binned1, boff1, off_ret, el1,
                                                    binned2, boff2, off_orig, el2);

    // ho = bf16(x_orig @ Wl1); xr = bf16(x_ret @ Wr1)   (one dispatch)
    gemm_lin<<<NBLK_HO + NBLK_XR, 256, 0, stream>>>(
        x_orig, x_ret, wtl1, wtr1, hoB, xrB);

    // r1s = bf16(relu(mean_agg(ho) + xr + bl1) * inv_s)   [200k x 128]
    gather_sage<<<(N_RET * 16) / 256, 256, 0, stream>>>(hoB, xrB, off_ret, el1, bl1, r1sB);

    // g = bf16(segment_sum(r1s))          [100k x 128]  (reuses hoB)
    gather_sum<<<(N_ORIG * 16) / 256, 256, 0, stream>>>(r1sB, off_orig, el2, hoB);

    // t = relu(g@Wg2*inv_d + bg2); out = t@Wout + bout   (fused, gather-free)
    gemm_t_out<<<(N_ORIG + 63) / 64, 256, 0, stream>>>(hoB, wtg2, wto, off_orig,
                                                       bg2, bout, out, N_ORIG);
}

// Round 10
// 231.298 us; speedup vs baseline: 1.0710x; 1.0710x over previous
//
#include <hip/hip_runtime.h>

#define N_RET  200000
#define N_ORIG 100000
#define N_EDGE 800000
#define NB_RET  ((N_RET  + 511) >> 9)   // 391 buckets of 512 nodes
#define NB_ORIG ((N_ORIG + 511) >> 9)   // 196
#define ECHUNK  2048
#define NCHUNK  ((N_EDGE + ECHUNK - 1) / ECHUNK)  // 391 edge-chunk blocks
#define NBLK_HO ((N_ORIG + 127) / 128)  // 782
#define NBLK_XR ((N_RET + 127) / 128)   // 1563

typedef __attribute__((ext_vector_type(8))) short bf16x8;   // 8 bf16 (4 VGPRs)
typedef __attribute__((ext_vector_type(4))) float f32x4;    // MFMA C/D

__device__ __forceinline__ ushort f2bf(float f) {
    union { float f; unsigned u; } v; v.f = f;
    unsigned r = v.u + 0x7FFFu + ((v.u >> 16) & 1u);   // RNE
    return (ushort)(r >> 16);
}
__device__ __forceinline__ float bf2f(ushort u) {
    union { unsigned u; float f; } v; v.u = ((unsigned)u) << 16;
    return v.f;
}
__device__ __forceinline__ int swz(int byteoff) {   // XOR swizzle for LDS tiles
    return byteoff ^ ((byteoff >> 4) & 0x70);
}

// ---------------- prep: all 4 weight transposes (bf16) + zero bucket counters ----------------
__global__ void prep_kernel(const float* __restrict__ Wl1, const float* __restrict__ Wr1,
                            const float* __restrict__ Wg2, const float* __restrict__ Wout,
                            ushort* __restrict__ wtl1, ushort* __restrict__ wtr1,
                            ushort* __restrict__ wtg2, ushort* __restrict__ wto,
                            int* __restrict__ bcnt) {
    const int b = blockIdx.x, t = threadIdx.x;
    if (b == 224) {
        for (int i = t; i < 1024; i += 256) bcnt[i] = 0;
        return;
    }
    const float* W; ushort* WT; int base, nshift;
    if (b < 64)       { W = Wl1;  WT = wtl1; base = b;       nshift = 7; }
    else if (b < 128) { W = Wr1;  WT = wtr1; base = b - 64;  nshift = 7; }
    else if (b < 192) { W = Wg2;  WT = wtg2; base = b - 128; nshift = 7; }
    else              { W = Wout; WT = wto;  base = b - 192; nshift = 6; }
    int i = base * 256 + t;
    int k = i >> nshift, n = i & ((1 << nshift) - 1);
    WT[n * 128 + k] = f2bf(W[i]);   // K = 128 for all
}

// ---------------- bucket-level histogram (both directions, 2048-edge chunks) ----------------
__global__ __launch_bounds__(256) void bucket_count(const int* __restrict__ ridx,
                                                    const int* __restrict__ cidx,
                                                    int* __restrict__ bcnt1,
                                                    int* __restrict__ bcnt2) {
    __shared__ int h1[512], h2[512];
    const int t = threadIdx.x;
    const int c0 = blockIdx.x * ECHUNK;
    for (int i = t; i < 512; i += 256) { h1[i] = 0; h2[i] = 0; }
    __syncthreads();
    for (int i = t; i < ECHUNK; i += 256) {
        int e = c0 + i;
        if (e < N_EDGE) {
            atomicAdd(&h1[ridx[e] >> 9], 1);
            atomicAdd(&h2[cidx[e] >> 9], 1);
        }
    }
    __syncthreads();
    for (int b = t; b < NB_RET; b += 256)
        if (h1[b]) atomicAdd(&bcnt1[b], h1[b]);
    for (int b = t; b < NB_ORIG; b += 256)
        if (h2[b]) atomicAdd(&bcnt2[b], h2[b]);
}

// ---------------- single-block scan of bucket counts -> bucket offsets + cursors ----------------
__global__ __launch_bounds__(256) void scan_buckets(const int* __restrict__ bcnt1,
                                                    int* __restrict__ boff1, int* __restrict__ bcur1,
                                                    const int* __restrict__ bcnt2,
                                                    int* __restrict__ boff2, int* __restrict__ bcur2,
                                                    int* __restrict__ off_ret,
                                                    int* __restrict__ off_orig) {
    __shared__ int sm[256];
    const int t = threadIdx.x;
    {
        int a0 = (2 * t     < NB_RET) ? bcnt1[2 * t]     : 0;
        int a1 = (2 * t + 1 < NB_RET) ? bcnt1[2 * t + 1] : 0;
        sm[t] = a0 + a1;
        __syncthreads();
        for (int d = 1; d < 256; d <<= 1) {
            int v = (t >= d) ? sm[t - d] : 0;
            __syncthreads(); sm[t] += v; __syncthreads();
        }
        int tb = t ? sm[t - 1] : 0;
        if (2 * t < NB_RET)     { boff1[2 * t]     = tb;      bcur1[2 * t]     = tb; }
        if (2 * t + 1 < NB_RET) { boff1[2 * t + 1] = tb + a0; bcur1[2 * t + 1] = tb + a0; }
        if (t == 0) { boff1[NB_RET] = N_EDGE; off_ret[N_RET] = N_EDGE; }
        __syncthreads();
    }
    {
        int a0 = (2 * t     < NB_ORIG) ? bcnt2[2 * t]     : 0;
        int a1 = (2 * t + 1 < NB_ORIG) ? bcnt2[2 * t + 1] : 0;
        sm[t] = a0 + a1;
        __syncthreads();
        for (int d = 1; d < 256; d <<= 1) {
            int v = (t >= d) ? sm[t - d] : 0;
            __syncthreads(); sm[t] += v; __syncthreads();
        }
        int tb = t ? sm[t - 1] : 0;
        if (2 * t < NB_ORIG)     { boff2[2 * t]     = tb;      bcur2[2 * t]     = tb; }
        if (2 * t + 1 < NB_ORIG) { boff2[2 * t + 1] = tb + a0; bcur2[2 * t + 1] = tb + a0; }
        if (t == 0) { boff2[NB_ORIG] = N_EDGE; off_orig[N_ORIG] = N_EDGE; }
    }
}

// ---------------- pass A (both dirs, 2048-edge chunks): bin by dst bucket ----------------
__global__ __launch_bounds__(256) void bin_both(const int* __restrict__ ridx,
                                                const int* __restrict__ cidx,
                                                int* __restrict__ bcur1, int* __restrict__ bcur2,
                                                int* __restrict__ binned1, int* __restrict__ binned2) {
    __shared__ int hist[512], base[512], lcur[512];
    const int t = threadIdx.x;
    const bool second = blockIdx.x >= NCHUNK;
    const int* dst = second ? cidx : ridx;
    const int* src = second ? ridx : cidx;
    int* bcur = second ? bcur2 : bcur1;
    int* binned = second ? binned2 : binned1;
    const int nbuckets = second ? NB_ORIG : NB_RET;
    const int c0 = (second ? blockIdx.x - NCHUNK : blockIdx.x) * ECHUNK;
    for (int i = t; i < 512; i += 256) { hist[i] = 0; lcur[i] = 0; }
    __syncthreads();
    for (int i = t; i < ECHUNK; i += 256) {
        int e = c0 + i;
        if (e < N_EDGE) atomicAdd(&hist[dst[e] >> 9], 1);
    }
    __syncthreads();
    for (int b = t; b < nbuckets; b += 256)
        base[b] = hist[b] > 0 ? atomicAdd(&bcur[b], hist[b]) : 0;
    __syncthreads();
    for (int i = t; i < ECHUNK; i += 256) {
        int e = c0 + i;
        if (e < N_EDGE) {
            int d = dst[e];
            int b = d >> 9;
            int r = atomicAdd(&lcur[b], 1);
            binned[base[b] + r] = ((d & 511) << 18) | src[e];
        }
    }
}

// ---------------- pass B (both dirs): per-bucket node-offset build + CSR fill ----------------
__global__ __launch_bounds__(256) void fill_both(const int* __restrict__ binned1,
                                                 const int* __restrict__ boff1,
                                                 int* __restrict__ off_ret, int* __restrict__ el1,
                                                 const int* __restrict__ binned2,
                                                 const int* __restrict__ boff2,
                                                 int* __restrict__ off_orig, int* __restrict__ el2) {
    __shared__ int hist[512];
    __shared__ int sm[256];
    const int t = threadIdx.x;
    const bool second = blockIdx.x >= NB_RET;
    const int bkt = second ? blockIdx.x - NB_RET : blockIdx.x;
    const int* binned = second ? binned2 : binned1;
    const int* boff = second ? boff2 : boff1;
    int* off = second ? off_orig : off_ret;
    int* el  = second ? el2 : el1;
    const int nnodes = second ? N_ORIG : N_RET;
    const int base = bkt << 9;
    const int nvalid = min(512, nnodes - base);
    const int s0 = boff[bkt], s1 = boff[bkt + 1];
    for (int i = t; i < 512; i += 256) hist[i] = 0;
    __syncthreads();
    for (int i = s0 + t; i < s1; i += 256)
        atomicAdd(&hist[binned[i] >> 18], 1);
    __syncthreads();
    int a0 = hist[2 * t], a1 = hist[2 * t + 1];
    sm[t] = a0 + a1;
    __syncthreads();
    for (int d = 1; d < 256; d <<= 1) {
        int v = (t >= d) ? sm[t - d] : 0;
        __syncthreads(); sm[t] += v; __syncthreads();
    }
    int tb = (t ? sm[t - 1] : 0) + s0;
    if (2 * t < nvalid)     off[base + 2 * t]     = tb;
    if (2 * t + 1 < nvalid) off[base + 2 * t + 1] = tb + a0;
    hist[2 * t] = tb;
    hist[2 * t + 1] = tb + a0;
    __syncthreads();
    for (int i = s0 + t; i < s1; i += 256) {
        int v = binned[i];
        int p = atomicAdd(&hist[v >> 18], 1);
        el[p] = v & 0x3FFFF;
    }
}

// ---------------- merged linear GEMMs v3: 128-row tiles, A global->reg, W^T LDS ----------------
// ho = bf16(x_orig@Wl1), xr = bf16(x_ret@Wr1). 2x64-row sub-tiles share staged W.
__global__ __launch_bounds__(256) void gemm_lin(const float* __restrict__ Ao,
                                                const float* __restrict__ Ar,
                                                const ushort* __restrict__ WTl,
                                                const ushort* __restrict__ WTr,
                                                ushort* __restrict__ hoB,
                                                ushort* __restrict__ xrB) {
    __shared__ ushort Wlds[128 * 128];   // 32 KB
    const int t = threadIdx.x;
    const bool second = blockIdx.x >= NBLK_HO;
    const float* A = second ? Ar : Ao;
    const ushort* WT = second ? WTr : WTl;
    ushort* outp = second ? xrB : hoB;
    const int M = second ? N_RET : N_ORIG;
    const int i0 = (second ? blockIdx.x - NBLK_HO : blockIdx.x) * 128;

    // stage W^T (reused by all 4 waves and both sub-tiles)
    #pragma unroll
    for (int it = 0; it < 8; ++it) {
        int idx = t + 256 * it;
        int n = idx >> 4, u = idx & 15;
        *(bf16x8*)&Wlds[swz(n * 256 + u * 16) >> 1] = *(const bf16x8*)&WT[idx * 8];
    }

    const int w = t >> 6, l = t & 63;
    const int r16 = l & 15, kg = l >> 4;

    // A fragments for 2 sub-tiles: 16 outstanding float4 loads before the barrier
    bf16x8 a[2][4];
    #pragma unroll
    for (int s = 0; s < 2; ++s) {
        int arow = min(i0 + s * 64 + 16 * w + r16, M - 1);
        #pragma unroll
        for (int ks = 0; ks < 4; ++ks) {
            const float* p = &A[(size_t)arow * 128 + ks * 32 + kg * 8];
            float4 v0 = *(const float4*)p;
            float4 v1 = *(const float4*)(p + 4);
            bf16x8 f;
            f[0] = (short)f2bf(v0.x); f[1] = (short)f2bf(v0.y);
            f[2] = (short)f2bf(v0.z); f[3] = (short)f2bf(v0.w);
            f[4] = (short)f2bf(v1.x); f[5] = (short)f2bf(v1.y);
            f[6] = (short)f2bf(v1.z); f[7] = (short)f2bf(v1.w);
            a[s][ks] = f;
        }
    }
    __syncthreads();

    f32x4 acc[2][8];
    #pragma unroll
    for (int s = 0; s < 2; ++s)
        #pragma unroll
        for (int cf = 0; cf < 8; ++cf) acc[s][cf] = (f32x4){0.f, 0.f, 0.f, 0.f};
    #pragma unroll
    for (int cf = 0; cf < 8; ++cf) {
        int n = cf * 16 + r16;
        #pragma unroll
        for (int ks = 0; ks < 4; ++ks) {
            bf16x8 b = *(const bf16x8*)&Wlds[swz(n * 256 + kg * 16 + ks * 64) >> 1];
            acc[0][cf] = __builtin_amdgcn_mfma_f32_16x16x32_bf16(a[0][ks], b, acc[0][cf], 0, 0, 0);
            acc[1][cf] = __builtin_amdgcn_mfma_f32_16x16x32_bf16(a[1][ks], b, acc[1][cf], 0, 0, 0);
        }
    }
    #pragma unroll
    for (int s = 0; s < 2; ++s)
        #pragma unroll
        for (int r = 0; r < 4; ++r) {
            int gr = i0 + s * 64 + 16 * w + 4 * kg + r;
            if (gr >= M) continue;
            #pragma unroll
            for (int cf = 0; cf < 8; ++cf)
                outp[(size_t)gr * 128 + cf * 16 + r16] = f2bf(acc[s][cf][r]);
        }
}

// ---------------- gather + SAGE epilogue: r1s = bf16(relu(mean_agg(ho) + xr + bl) * inv_s) ----------------
__global__ void gather_sage(const ushort* __restrict__ ho, const ushort* __restrict__ xr,
                            const int* __restrict__ off, const int* __restrict__ slist,
                            const float* __restrict__ bl, ushort* __restrict__ r1s) {
    int gt = blockIdx.x * 256 + threadIdx.x;
    int node = gt >> 4;
    if (node >= N_RET) return;
    int o8 = gt & 15;
    int s = off[node], e = off[node + 1];
    float acc[8] = {0.f, 0.f, 0.f, 0.f, 0.f, 0.f, 0.f, 0.f};
    for (int i = s; i < e; ++i) {
        int sn = slist[i];
        bf16x8 v = *(const bf16x8*)&ho[(size_t)sn * 128 + o8 * 8];
        #pragma unroll
        for (int j = 0; j < 8; ++j) acc[j] += bf2f((ushort)v[j]);
    }
    int deg = e - s;
    float rinv = 1.0f / fmaxf((float)deg, 1.0f);
    float sinv = deg > 0 ? rsqrtf((float)deg) : 0.f;
    bf16x8 xv = *(const bf16x8*)&xr[(size_t)node * 128 + o8 * 8];
    bf16x8 ov;
    #pragma unroll
    for (int j = 0; j < 8; ++j) {
        float v = fmaxf(acc[j] * rinv + bf2f((ushort)xv[j]) + bl[o8 * 8 + j], 0.f) * sinv;
        ov[j] = (short)f2bf(v);
    }
    *(bf16x8*)&r1s[(size_t)node * 128 + o8 * 8] = ov;
}

// ---------------- gather sum: g = bf16(sum of r1s rows) ----------------
__global__ void gather_sum(const ushort* __restrict__ src,
                           const int* __restrict__ off, const int* __restrict__ slist,
                           ushort* __restrict__ dst) {
    int gt = blockIdx.x * 256 + threadIdx.x;
    int node = gt >> 4;
    if (node >= N_ORIG) return;
    int o8 = gt & 15;
    int s = off[node], e = off[node + 1];
    float acc[8] = {0.f, 0.f, 0.f, 0.f, 0.f, 0.f, 0.f, 0.f};
    for (int i = s; i < e; ++i) {
        int sn = slist[i];
        bf16x8 v = *(const bf16x8*)&src[(size_t)sn * 128 + o8 * 8];
        #pragma unroll
        for (int j = 0; j < 8; ++j) acc[j] += bf2f((ushort)v[j]);
    }
    bf16x8 ov;
    #pragma unroll
    for (int j = 0; j < 8; ++j) ov[j] = (short)f2bf(acc[j]);
    *(bf16x8*)&dst[(size_t)node * 128 + o8 * 8] = ov;
}

// ---- fused double-GEMM (NO gather): t = relu(g@Wg2*inv_d + bg2); out = t@Wout + bout ----
__global__ __launch_bounds__(256) void gemm_t_out(
    const ushort* __restrict__ g, const ushort* __restrict__ WTg,
    const ushort* __restrict__ WTo, const int* __restrict__ off,
    const float* __restrict__ bg, const float* __restrict__ bo,
    float* __restrict__ out, int M) {
    __shared__ ushort Alds[64 * 128];    // 16 KB
    __shared__ ushort Wlds[128 * 128];   // 32 KB
    const int t = threadIdx.x;
    const int i0 = blockIdx.x * 64;

    // stage Wg2^T + A (bf16 direct copy)
    #pragma unroll
    for (int it = 0; it < 8; ++it) {
        int idx = t + 256 * it;
        int n = idx >> 4, u = idx & 15;
        *(bf16x8*)&Wlds[swz(n * 256 + u * 16) >> 1] = *(const bf16x8*)&WTg[idx * 8];
    }
    #pragma unroll
    for (int it = 0; it < 4; ++it) {
        int idx = t + 256 * it;
        int row = idx >> 4, u = idx & 15;
        int gr = min(i0 + row, M - 1);
        bf16x8 v = *(const bf16x8*)&g[(size_t)gr * 128 + u * 8];
        *(bf16x8*)&Alds[swz(row * 256 + u * 16) >> 1] = v;
    }
    __syncthreads();

    const int w = t >> 6, l = t & 63;
    const int r16 = l & 15, kg = l >> 4;
    const int arow = 16 * w + r16;

    bf16x8 a[4];
    #pragma unroll
    for (int ks = 0; ks < 4; ++ks)
        a[ks] = *(const bf16x8*)&Alds[swz(arow * 256 + kg * 16 + ks * 64) >> 1];
    f32x4 acc[8];
    #pragma unroll
    for (int cf = 0; cf < 8; ++cf) acc[cf] = (f32x4){0.f, 0.f, 0.f, 0.f};
    #pragma unroll
    for (int cf = 0; cf < 8; ++cf) {
        int n = cf * 16 + r16;
        #pragma unroll
        for (int ks = 0; ks < 4; ++ks) {
            bf16x8 b = *(const bf16x8*)&Wlds[swz(n * 256 + kg * 16 + ks * 64) >> 1];
            acc[cf] = __builtin_amdgcn_mfma_f32_16x16x32_bf16(a[ks], b, acc[cf], 0, 0, 0);
        }
    }
    __syncthreads();   // Alds a-frags in regs, Wlds consumed -> both reusable

    // t-tile = relu(acc*inv_d + bg) -> Alds (bf16, swizzled); stage Wout^T -> Wlds
    #pragma unroll
    for (int r = 0; r < 4; ++r) {
        int row = 16 * w + 4 * kg + r;
        int grc = min(i0 + row, M - 1);
        int dg = off[grc + 1] - off[grc];
        float di = dg > 0 ? rsqrtf((float)dg) : 0.f;
        #pragma unroll
        for (int cf = 0; cf < 8; ++cf) {
            int col = cf * 16 + r16;
            float v = fmaxf(acc[cf][r] * di + bg[col], 0.f);
            Alds[swz(row * 256 + col * 2) >> 1] = f2bf(v);
        }
    }
    #pragma unroll
    for (int it = 0; it < 4; ++it) {
        int idx = t + 256 * it;
        int n = idx >> 4, u = idx & 15;
        *(bf16x8*)&Wlds[swz(n * 256 + u * 16) >> 1] = *(const bf16x8*)&WTo[idx * 8];
    }
    __syncthreads();

    bf16x8 a2[4];
    #pragma unroll
    for (int ks = 0; ks < 4; ++ks)
        a2[ks] = *(const bf16x8*)&Alds[swz(arow * 256 + kg * 16 + ks * 64) >> 1];
    f32x4 acc2[4];
    #pragma unroll
    for (int cf = 0; cf < 4; ++cf) acc2[cf] = (f32x4){0.f, 0.f, 0.f, 0.f};
    #pragma unroll
    for (int cf = 0; cf < 4; ++cf) {
        int n = cf * 16 + r16;
        #pragma unroll
        for (int ks = 0; ks < 4; ++ks) {
            bf16x8 b = *(const bf16x8*)&Wlds[swz(n * 256 + kg * 16 + ks * 64) >> 1];
            acc2[cf] = __builtin_amdgcn_mfma_f32_16x16x32_bf16(a2[ks], b, acc2[cf], 0, 0, 0);
        }
    }
    #pragma unroll
    for (int r = 0; r < 4; ++r) {
        int gr = i0 + 16 * w + 4 * kg + r;
        if (gr >= M) continue;
        #pragma unroll
        for (int cf = 0; cf < 4; ++cf) {
            int col = cf * 16 + r16;
            out[(size_t)gr * 64 + col] = acc2[cf][r] + bo[col];
        }
    }
}

extern "C" void kernel_launch(void* const* d_in, const int* in_sizes, int n_in,
                              void* d_out, int out_size, void* d_ws, size_t ws_size,
                              hipStream_t stream) {
    const float* x_ret    = (const float*)d_in[0];
    const float* x_orig   = (const float*)d_in[1];
    const int*   ret_idx  = (const int*)d_in[2];
    const int*   orig_idx = (const int*)d_in[3];
    const float* Wl1  = (const float*)d_in[6];
    const float* bl1  = (const float*)d_in[7];
    const float* Wr1  = (const float*)d_in[8];
    const float* Wg2  = (const float*)d_in[9];
    const float* bg2  = (const float*)d_in[10];
    const float* Wout = (const float*)d_in[14];
    const float* bout = (const float*)d_in[15];
    float* out = (float*)d_out;

    // workspace layout
    ushort* hoB  = (ushort*)d_ws;                       // 100k*128 bf16 (ho, later g)
    ushort* xrB  = hoB + (size_t)N_ORIG * 128;          // 200k*128 bf16
    ushort* r1sB = xrB + (size_t)N_RET * 128;           // 200k*128 bf16
    ushort* wtl1 = r1sB + (size_t)N_RET * 128;          // 16384
    ushort* wtr1 = wtl1 + 16384;                        // 16384
    ushort* wtg2 = wtr1 + 16384;                        // 16384
    ushort* wto  = wtg2 + 16384;                        // 8192
    int* off_ret  = (int*)(wto + 8192);                 // N_RET+1
    int* off_orig = off_ret + N_RET + 1;                // N_ORIG+1
    int* bcnt1    = off_orig + N_ORIG + 1;              // 512
    int* bcnt2    = bcnt1 + 512;                        // 512 (adjacent for one-pass zero)
    int* boff1    = bcnt2 + 512;                        // 512
    int* boff2    = boff1 + 512;                        // 512
    int* bcur1    = boff2 + 512;                        // 512
    int* bcur2    = bcur1 + 512;                        // 512
    int* el1      = bcur2 + 512;                        // N_EDGE (src=orig, grouped by ret)
    int* el2      = el1 + N_EDGE;                       // N_EDGE (src=ret, grouped by orig)
    int* binned1  = el2 + N_EDGE;                       // N_EDGE packed
    int* binned2  = binned1 + N_EDGE;                   // N_EDGE packed

    prep_kernel<<<225, 256, 0, stream>>>(Wl1, Wr1, Wg2, Wout, wtl1, wtr1, wtg2, wto, bcnt1);

    bucket_count<<<NCHUNK, 256, 0, stream>>>(ret_idx, orig_idx, bcnt1, bcnt2);
    scan_buckets<<<1, 256, 0, stream>>>(bcnt1, boff1, bcur1, bcnt2, boff2, bcur2,
                                        off_ret, off_orig);
    bin_both<<<2 * NCHUNK, 256, 0, stream>>>(ret_idx, orig_idx, bcur1, bcur2, binned1, binned2);
    fill_both<<<NB_RET + NB_ORIG, 256, 0, stream>>>(binned1, boff1, off_ret, el1,
                                                    binned2, boff2, off_orig, el2);

    // ho = bf16(x_orig @ Wl1); xr = bf16(x_ret @ Wr1)   (one dispatch, 128-row tiles)
    gemm_lin<<<NBLK_HO + NBLK_XR, 256, 0, stream>>>(
        x_orig, x_ret, wtl1, wtr1, hoB, xrB);

    // r1s = bf16(relu(mean_agg(ho) + xr + bl1) * inv_s)   [200k x 128]
    gather_sage<<<(N_RET * 16) / 256, 256, 0, stream>>>(hoB, xrB, off_ret, el1, bl1, r1sB);

    // g = bf16(segment_sum(r1s))          [100k x 128]  (reuses hoB)
    gather_sum<<<(N_ORIG * 16) / 256, 256, 0, stream>>>(r1sB, off_orig, el2, hoB);

    // t = relu(g@Wg2*inv_d + bg2); out = t@Wout + bout   (fused, gather-free)
    gemm_t_out<<<(N_ORIG + 63) / 64, 256, 0, stream>>>(hoB, wtg2, wto, off_orig,
                                                       bg2, bout, out, N_ORIG);
}

// Round 11
// 217.903 us; speedup vs baseline: 1.1368x; 1.0615x over previous
//
#include <hip/hip_runtime.h>

#define N_RET  200000
#define N_ORIG 100000
#define N_EDGE 800000
#define NB_RET  ((N_RET  + 511) >> 9)   // 391 buckets of 512 nodes
#define NB_ORIG ((N_ORIG + 511) >> 9)   // 196
#define ECHUNK  2048
#define NCHUNK  ((N_EDGE + ECHUNK - 1) / ECHUNK)  // 391 edge-chunk blocks
#define NBLK_HO ((N_ORIG + 63) / 64)    // 1563
#define NBLK_XR ((N_RET + 63) / 64)     // 3125

typedef __attribute__((ext_vector_type(8))) short bf16x8;   // 8 bf16 (4 VGPRs)
typedef __attribute__((ext_vector_type(4))) float f32x4;    // MFMA C/D

__device__ __forceinline__ ushort f2bf(float f) {
    union { float f; unsigned u; } v; v.f = f;
    unsigned r = v.u + 0x7FFFu + ((v.u >> 16) & 1u);   // RNE
    return (ushort)(r >> 16);
}
__device__ __forceinline__ float bf2f(ushort u) {
    union { unsigned u; float f; } v; v.u = ((unsigned)u) << 16;
    return v.f;
}
__device__ __forceinline__ int swz(int byteoff) {   // XOR swizzle for LDS tiles
    return byteoff ^ ((byteoff >> 4) & 0x70);
}

// ---------------- prep: all 4 weight transposes (bf16) + zero bucket counters ----------------
__global__ void prep_kernel(const float* __restrict__ Wl1, const float* __restrict__ Wr1,
                            const float* __restrict__ Wg2, const float* __restrict__ Wout,
                            ushort* __restrict__ wtl1, ushort* __restrict__ wtr1,
                            ushort* __restrict__ wtg2, ushort* __restrict__ wto,
                            int* __restrict__ bcnt) {
    const int b = blockIdx.x, t = threadIdx.x;
    if (b == 224) {
        for (int i = t; i < 1024; i += 256) bcnt[i] = 0;
        return;
    }
    const float* W; ushort* WT; int base, nshift;
    if (b < 64)       { W = Wl1;  WT = wtl1; base = b;       nshift = 7; }
    else if (b < 128) { W = Wr1;  WT = wtr1; base = b - 64;  nshift = 7; }
    else if (b < 192) { W = Wg2;  WT = wtg2; base = b - 128; nshift = 7; }
    else              { W = Wout; WT = wto;  base = b - 192; nshift = 6; }
    int i = base * 256 + t;
    int k = i >> nshift, n = i & ((1 << nshift) - 1);
    WT[n * 128 + k] = f2bf(W[i]);   // K = 128 for all
}

// ---------------- bucket-level histogram (both directions, 2048-edge chunks) ----------------
__global__ __launch_bounds__(256) void bucket_count(const int* __restrict__ ridx,
                                                    const int* __restrict__ cidx,
                                                    int* __restrict__ bcnt1,
                                                    int* __restrict__ bcnt2) {
    __shared__ int h1[512], h2[512];
    const int t = threadIdx.x;
    const int c0 = blockIdx.x * ECHUNK;
    for (int i = t; i < 512; i += 256) { h1[i] = 0; h2[i] = 0; }
    __syncthreads();
    for (int i = t; i < ECHUNK; i += 256) {
        int e = c0 + i;
        if (e < N_EDGE) {
            atomicAdd(&h1[ridx[e] >> 9], 1);
            atomicAdd(&h2[cidx[e] >> 9], 1);
        }
    }
    __syncthreads();
    for (int b = t; b < NB_RET; b += 256)
        if (h1[b]) atomicAdd(&bcnt1[b], h1[b]);
    for (int b = t; b < NB_ORIG; b += 256)
        if (h2[b]) atomicAdd(&bcnt2[b], h2[b]);
}

// ---------------- single-block scan of bucket counts -> bucket offsets + cursors ----------------
__global__ __launch_bounds__(256) void scan_buckets(const int* __restrict__ bcnt1,
                                                    int* __restrict__ boff1, int* __restrict__ bcur1,
                                                    const int* __restrict__ bcnt2,
                                                    int* __restrict__ boff2, int* __restrict__ bcur2,
                                                    int* __restrict__ off_ret,
                                                    int* __restrict__ off_orig) {
    __shared__ int sm[256];
    const int t = threadIdx.x;
    {
        int a0 = (2 * t     < NB_RET) ? bcnt1[2 * t]     : 0;
        int a1 = (2 * t + 1 < NB_RET) ? bcnt1[2 * t + 1] : 0;
        sm[t] = a0 + a1;
        __syncthreads();
        for (int d = 1; d < 256; d <<= 1) {
            int v = (t >= d) ? sm[t - d] : 0;
            __syncthreads(); sm[t] += v; __syncthreads();
        }
        int tb = t ? sm[t - 1] : 0;
        if (2 * t < NB_RET)     { boff1[2 * t]     = tb;      bcur1[2 * t]     = tb; }
        if (2 * t + 1 < NB_RET) { boff1[2 * t + 1] = tb + a0; bcur1[2 * t + 1] = tb + a0; }
        if (t == 0) { boff1[NB_RET] = N_EDGE; off_ret[N_RET] = N_EDGE; }
        __syncthreads();
    }
    {
        int a0 = (2 * t     < NB_ORIG) ? bcnt2[2 * t]     : 0;
        int a1 = (2 * t + 1 < NB_ORIG) ? bcnt2[2 * t + 1] : 0;
        sm[t] = a0 + a1;
        __syncthreads();
        for (int d = 1; d < 256; d <<= 1) {
            int v = (t >= d) ? sm[t - d] : 0;
            __syncthreads(); sm[t] += v; __syncthreads();
        }
        int tb = t ? sm[t - 1] : 0;
        if (2 * t < NB_ORIG)     { boff2[2 * t]     = tb;      bcur2[2 * t]     = tb; }
        if (2 * t + 1 < NB_ORIG) { boff2[2 * t + 1] = tb + a0; bcur2[2 * t + 1] = tb + a0; }
        if (t == 0) { boff2[NB_ORIG] = N_EDGE; off_orig[N_ORIG] = N_EDGE; }
    }
}

// ---------------- pass A (both dirs, 2048-edge chunks): bin by dst bucket ----------------
__global__ __launch_bounds__(256) void bin_both(const int* __restrict__ ridx,
                                                const int* __restrict__ cidx,
                                                int* __restrict__ bcur1, int* __restrict__ bcur2,
                                                int* __restrict__ binned1, int* __restrict__ binned2) {
    __shared__ int hist[512], base[512], lcur[512];
    const int t = threadIdx.x;
    const bool second = blockIdx.x >= NCHUNK;
    const int* dst = second ? cidx : ridx;
    const int* src = second ? ridx : cidx;
    int* bcur = second ? bcur2 : bcur1;
    int* binned = second ? binned2 : binned1;
    const int nbuckets = second ? NB_ORIG : NB_RET;
    const int c0 = (second ? blockIdx.x - NCHUNK : blockIdx.x) * ECHUNK;
    for (int i = t; i < 512; i += 256) { hist[i] = 0; lcur[i] = 0; }
    __syncthreads();
    for (int i = t; i < ECHUNK; i += 256) {
        int e = c0 + i;
        if (e < N_EDGE) atomicAdd(&hist[dst[e] >> 9], 1);
    }
    __syncthreads();
    for (int b = t; b < nbuckets; b += 256)
        base[b] = hist[b] > 0 ? atomicAdd(&bcur[b], hist[b]) : 0;
    __syncthreads();
    for (int i = t; i < ECHUNK; i += 256) {
        int e = c0 + i;
        if (e < N_EDGE) {
            int d = dst[e];
            int b = d >> 9;
            int r = atomicAdd(&lcur[b], 1);
            binned[base[b] + r] = ((d & 511) << 18) | src[e];
        }
    }
}

// ---------------- pass B (both dirs): per-bucket node-offset build + CSR fill ----------------
__global__ __launch_bounds__(256) void fill_both(const int* __restrict__ binned1,
                                                 const int* __restrict__ boff1,
                                                 int* __restrict__ off_ret, int* __restrict__ el1,
                                                 const int* __restrict__ binned2,
                                                 const int* __restrict__ boff2,
                                                 int* __restrict__ off_orig, int* __restrict__ el2) {
    __shared__ int hist[512];
    __shared__ int sm[256];
    const int t = threadIdx.x;
    const bool second = blockIdx.x >= NB_RET;
    const int bkt = second ? blockIdx.x - NB_RET : blockIdx.x;
    const int* binned = second ? binned2 : binned1;
    const int* boff = second ? boff2 : boff1;
    int* off = second ? off_orig : off_ret;
    int* el  = second ? el2 : el1;
    const int nnodes = second ? N_ORIG : N_RET;
    const int base = bkt << 9;
    const int nvalid = min(512, nnodes - base);
    const int s0 = boff[bkt], s1 = boff[bkt + 1];
    for (int i = t; i < 512; i += 256) hist[i] = 0;
    __syncthreads();
    for (int i = s0 + t; i < s1; i += 256)
        atomicAdd(&hist[binned[i] >> 18], 1);
    __syncthreads();
    int a0 = hist[2 * t], a1 = hist[2 * t + 1];
    sm[t] = a0 + a1;
    __syncthreads();
    for (int d = 1; d < 256; d <<= 1) {
        int v = (t >= d) ? sm[t - d] : 0;
        __syncthreads(); sm[t] += v; __syncthreads();
    }
    int tb = (t ? sm[t - 1] : 0) + s0;
    if (2 * t < nvalid)     off[base + 2 * t]     = tb;
    if (2 * t + 1 < nvalid) off[base + 2 * t + 1] = tb + a0;
    hist[2 * t] = tb;
    hist[2 * t + 1] = tb + a0;
    __syncthreads();
    for (int i = s0 + t; i < s1; i += 256) {
        int v = binned[i];
        int p = atomicAdd(&hist[v >> 18], 1);
        el[p] = v & 0x3FFFF;
    }
}

// ---------------- merged linear GEMMs v4: 64-row tile, explicit-MLP A loads, ----------------
// ---------------- LDS-staged coalesced bf16 stores. W^T in LDS (reused as out-stage). ------
__global__ __launch_bounds__(256) void gemm_lin(const float* __restrict__ Ao,
                                                const float* __restrict__ Ar,
                                                const ushort* __restrict__ WTl,
                                                const ushort* __restrict__ WTr,
                                                ushort* __restrict__ hoB,
                                                ushort* __restrict__ xrB) {
    __shared__ ushort Wlds[128 * 128];   // 32 KB; first 16 KB reused as C-stage
    const int t = threadIdx.x;
    const bool second = blockIdx.x >= NBLK_HO;
    const float* A = second ? Ar : Ao;
    const ushort* WT = second ? WTr : WTl;
    ushort* outp = second ? xrB : hoB;
    const int M = second ? N_RET : N_ORIG;
    const int i0 = (second ? blockIdx.x - NBLK_HO : blockIdx.x) * 64;

    // stage W^T (reused by all 4 waves)
    #pragma unroll
    for (int it = 0; it < 8; ++it) {
        int idx = t + 256 * it;
        int n = idx >> 4, u = idx & 15;
        *(bf16x8*)&Wlds[swz(n * 256 + u * 16) >> 1] = *(const bf16x8*)&WT[idx * 8];
    }

    const int w = t >> 6, l = t & 63;
    const int r16 = l & 15, kg = l >> 4;
    const int arow = min(i0 + 16 * w + r16, M - 1);

    // A: issue all 8 float4 loads first (8-deep MLP), then convert
    float4 v[8];
    #pragma unroll
    for (int j = 0; j < 8; ++j)
        v[j] = *(const float4*)&A[(size_t)arow * 128 + (j >> 1) * 32 + kg * 8 + (j & 1) * 4];
    bf16x8 a[4];
    #pragma unroll
    for (int ks = 0; ks < 4; ++ks) {
        float4 v0 = v[2 * ks], v1 = v[2 * ks + 1];
        bf16x8 f;
        f[0] = (short)f2bf(v0.x); f[1] = (short)f2bf(v0.y);
        f[2] = (short)f2bf(v0.z); f[3] = (short)f2bf(v0.w);
        f[4] = (short)f2bf(v1.x); f[5] = (short)f2bf(v1.y);
        f[6] = (short)f2bf(v1.z); f[7] = (short)f2bf(v1.w);
        a[ks] = f;
    }
    __syncthreads();

    f32x4 acc[8];
    #pragma unroll
    for (int cf = 0; cf < 8; ++cf) acc[cf] = (f32x4){0.f, 0.f, 0.f, 0.f};
    #pragma unroll
    for (int cf = 0; cf < 8; ++cf) {
        int n = cf * 16 + r16;
        #pragma unroll
        for (int ks = 0; ks < 4; ++ks) {
            bf16x8 b = *(const bf16x8*)&Wlds[swz(n * 256 + kg * 16 + ks * 64) >> 1];
            acc[cf] = __builtin_amdgcn_mfma_f32_16x16x32_bf16(a[ks], b, acc[cf], 0, 0, 0);
        }
    }
    __syncthreads();   // Wlds fully consumed -> reuse as C staging

    // stage C as bf16 into LDS (swizzled), then store coalesced (1 KB/wave-instr)
    #pragma unroll
    for (int r = 0; r < 4; ++r) {
        int row = 16 * w + 4 * kg + r;
        #pragma unroll
        for (int cf = 0; cf < 8; ++cf) {
            int ad = row * 256 + (cf * 16 + r16) * 2;
            Wlds[swz(ad) >> 1] = f2bf(acc[cf][r]);
        }
    }
    __syncthreads();

    const size_t obase = (size_t)i0 * 128;   // ushort elements
    #pragma unroll
    for (int j = 0; j < 4; ++j) {
        int lb = j * 4096 + t * 16;          // byte offset in 16 KB tile
        bf16x8 val = *(const bf16x8*)&Wlds[swz(lb) >> 1];
        if (i0 + (lb >> 8) < M)
            *(bf16x8*)&outp[obase + (lb >> 1)] = val;
    }
}

// ---------------- gather + SAGE epilogue: r1s = bf16(relu(mean_agg(ho) + xr + bl) * inv_s) ----------------
__global__ void gather_sage(const ushort* __restrict__ ho, const ushort* __restrict__ xr,
                            const int* __restrict__ off, const int* __restrict__ slist,
                            const float* __restrict__ bl, ushort* __restrict__ r1s) {
    int gt = blockIdx.x * 256 + threadIdx.x;
    int node = gt >> 4;
    if (node >= N_RET) return;
    int o8 = gt & 15;
    int s = off[node], e = off[node + 1];
    float acc[8] = {0.f, 0.f, 0.f, 0.f, 0.f, 0.f, 0.f, 0.f};
    for (int i = s; i < e; ++i) {
        int sn = slist[i];
        bf16x8 v = *(const bf16x8*)&ho[(size_t)sn * 128 + o8 * 8];
        #pragma unroll
        for (int j = 0; j < 8; ++j) acc[j] += bf2f((ushort)v[j]);
    }
    int deg = e - s;
    float rinv = 1.0f / fmaxf((float)deg, 1.0f);
    float sinv = deg > 0 ? rsqrtf((float)deg) : 0.f;
    bf16x8 xv = *(const bf16x8*)&xr[(size_t)node * 128 + o8 * 8];
    bf16x8 ov;
    #pragma unroll
    for (int j = 0; j < 8; ++j) {
        float v = fmaxf(acc[j] * rinv + bf2f((ushort)xv[j]) + bl[o8 * 8 + j], 0.f) * sinv;
        ov[j] = (short)f2bf(v);
    }
    *(bf16x8*)&r1s[(size_t)node * 128 + o8 * 8] = ov;
}

// ---------------- gather sum: g = bf16(sum of r1s rows) ----------------
__global__ void gather_sum(const ushort* __restrict__ src,
                           const int* __restrict__ off, const int* __restrict__ slist,
                           ushort* __restrict__ dst) {
    int gt = blockIdx.x * 256 + threadIdx.x;
    int node = gt >> 4;
    if (node >= N_ORIG) return;
    int o8 = gt & 15;
    int s = off[node], e = off[node + 1];
    float acc[8] = {0.f, 0.f, 0.f, 0.f, 0.f, 0.f, 0.f, 0.f};
    for (int i = s; i < e; ++i) {
        int sn = slist[i];
        bf16x8 v = *(const bf16x8*)&src[(size_t)sn * 128 + o8 * 8];
        #pragma unroll
        for (int j = 0; j < 8; ++j) acc[j] += bf2f((ushort)v[j]);
    }
    bf16x8 ov;
    #pragma unroll
    for (int j = 0; j < 8; ++j) ov[j] = (short)f2bf(acc[j]);
    *(bf16x8*)&dst[(size_t)node * 128 + o8 * 8] = ov;
}

// ---- fused double-GEMM (NO gather): t = relu(g@Wg2*inv_d + bg2); out = t@Wout + bout ----
__global__ __launch_bounds__(256) void gemm_t_out(
    const ushort* __restrict__ g, const ushort* __restrict__ WTg,
    const ushort* __restrict__ WTo, const int* __restrict__ off,
    const float* __restrict__ bg, const float* __restrict__ bo,
    float* __restrict__ out, int M) {
    __shared__ ushort Alds[64 * 128];    // 16 KB
    __shared__ ushort Wlds[128 * 128];   // 32 KB
    const int t = threadIdx.x;
    const int i0 = blockIdx.x * 64;

    // stage Wg2^T + A (bf16 direct copy)
    #pragma unroll
    for (int it = 0; it < 8; ++it) {
        int idx = t + 256 * it;
        int n = idx >> 4, u = idx & 15;
        *(bf16x8*)&Wlds[swz(n * 256 + u * 16) >> 1] = *(const bf16x8*)&WTg[idx * 8];
    }
    #pragma unroll
    for (int it = 0; it < 4; ++it) {
        int idx = t + 256 * it;
        int row = idx >> 4, u = idx & 15;
        int gr = min(i0 + row, M - 1);
        bf16x8 v = *(const bf16x8*)&g[(size_t)gr * 128 + u * 8];
        *(bf16x8*)&Alds[swz(row * 256 + u * 16) >> 1] = v;
    }
    __syncthreads();

    const int w = t >> 6, l = t & 63;
    const int r16 = l & 15, kg = l >> 4;
    const int arow = 16 * w + r16;

    bf16x8 a[4];
    #pragma unroll
    for (int ks = 0; ks < 4; ++ks)
        a[ks] = *(const bf16x8*)&Alds[swz(arow * 256 + kg * 16 + ks * 64) >> 1];
    f32x4 acc[8];
    #pragma unroll
    for (int cf = 0; cf < 8; ++cf) acc[cf] = (f32x4){0.f, 0.f, 0.f, 0.f};
    #pragma unroll
    for (int cf = 0; cf < 8; ++cf) {
        int n = cf * 16 + r16;
        #pragma unroll
        for (int ks = 0; ks < 4; ++ks) {
            bf16x8 b = *(const bf16x8*)&Wlds[swz(n * 256 + kg * 16 + ks * 64) >> 1];
            acc[cf] = __builtin_amdgcn_mfma_f32_16x16x32_bf16(a[ks], b, acc[cf], 0, 0, 0);
        }
    }
    __syncthreads();   // Alds a-frags in regs, Wlds consumed -> both reusable

    // t-tile = relu(acc*inv_d + bg) -> Alds (bf16, swizzled); stage Wout^T -> Wlds
    #pragma unroll
    for (int r = 0; r < 4; ++r) {
        int row = 16 * w + 4 * kg + r;
        int grc = min(i0 + row, M - 1);
        int dg = off[grc + 1] - off[grc];
        float di = dg > 0 ? rsqrtf((float)dg) : 0.f;
        #pragma unroll
        for (int cf = 0; cf < 8; ++cf) {
            int col = cf * 16 + r16;
            float v = fmaxf(acc[cf][r] * di + bg[col], 0.f);
            Alds[swz(row * 256 + col * 2) >> 1] = f2bf(v);
        }
    }
    #pragma unroll
    for (int it = 0; it < 4; ++it) {
        int idx = t + 256 * it;
        int n = idx >> 4, u = idx & 15;
        *(bf16x8*)&Wlds[swz(n * 256 + u * 16) >> 1] = *(const bf16x8*)&WTo[idx * 8];
    }
    __syncthreads();

    bf16x8 a2[4];
    #pragma unroll
    for (int ks = 0; ks < 4; ++ks)
        a2[ks] = *(const bf16x8*)&Alds[swz(arow * 256 + kg * 16 + ks * 64) >> 1];
    f32x4 acc2[4];
    #pragma unroll
    for (int cf = 0; cf < 4; ++cf) acc2[cf] = (f32x4){0.f, 0.f, 0.f, 0.f};
    #pragma unroll
    for (int cf = 0; cf < 4; ++cf) {
        int n = cf * 16 + r16;
        #pragma unroll
        for (int ks = 0; ks < 4; ++ks) {
            bf16x8 b = *(const bf16x8*)&Wlds[swz(n * 256 + kg * 16 + ks * 64) >> 1];
            acc2[cf] = __builtin_amdgcn_mfma_f32_16x16x32_bf16(a2[ks], b, acc2[cf], 0, 0, 0);
        }
    }
    #pragma unroll
    for (int r = 0; r < 4; ++r) {
        int gr = i0 + 16 * w + 4 * kg + r;
        if (gr >= M) continue;
        #pragma unroll
        for (int cf = 0; cf < 4; ++cf) {
            int col = cf * 16 + r16;
            out[(size_t)gr * 64 + col] = acc2[cf][r] + bo[col];
        }
    }
}

extern "C" void kernel_launch(void* const* d_in, const int* in_sizes, int n_in,
                              void* d_out, int out_size, void* d_ws, size_t ws_size,
                              hipStream_t stream) {
    const float* x_ret    = (const float*)d_in[0];
    const float* x_orig   = (const float*)d_in[1];
    const int*   ret_idx  = (const int*)d_in[2];
    const int*   orig_idx = (const int*)d_in[3];
    const float* Wl1  = (const float*)d_in[6];
    const float* bl1  = (const float*)d_in[7];
    const float* Wr1  = (const float*)d_in[8];
    const float* Wg2  = (const float*)d_in[9];
    const float* bg2  = (const float*)d_in[10];
    const float* Wout = (const float*)d_in[14];
    const float* bout = (const float*)d_in[15];
    float* out = (float*)d_out;

    // workspace layout
    ushort* hoB  = (ushort*)d_ws;                       // 100k*128 bf16 (ho, later g)
    ushort* xrB  = hoB + (size_t)N_ORIG * 128;          // 200k*128 bf16
    ushort* r1sB = xrB + (size_t)N_RET * 128;           // 200k*128 bf16
    ushort* wtl1 = r1sB + (size_t)N_RET * 128;          // 16384
    ushort* wtr1 = wtl1 + 16384;                        // 16384
    ushort* wtg2 = wtr1 + 16384;                        // 16384
    ushort* wto  = wtg2 + 16384;                        // 8192
    int* off_ret  = (int*)(wto + 8192);                 // N_RET+1
    int* off_orig = off_ret + N_RET + 1;                // N_ORIG+1
    int* bcnt1    = off_orig + N_ORIG + 1;              // 512
    int* bcnt2    = bcnt1 + 512;                        // 512 (adjacent for one-pass zero)
    int* boff1    = bcnt2 + 512;                        // 512
    int* boff2    = boff1 + 512;                        // 512
    int* bcur1    = boff2 + 512;                        // 512
    int* bcur2    = bcur1 + 512;                        // 512
    int* el1      = bcur2 + 512;                        // N_EDGE (src=orig, grouped by ret)
    int* el2      = el1 + N_EDGE;                       // N_EDGE (src=ret, grouped by orig)
    int* binned1  = el2 + N_EDGE;                       // N_EDGE packed
    int* binned2  = binned1 + N_EDGE;                   // N_EDGE packed

    prep_kernel<<<225, 256, 0, stream>>>(Wl1, Wr1, Wg2, Wout, wtl1, wtr1, wtg2, wto, bcnt1);

    bucket_count<<<NCHUNK, 256, 0, stream>>>(ret_idx, orig_idx, bcnt1, bcnt2);
    scan_buckets<<<1, 256, 0, stream>>>(bcnt1, boff1, bcur1, bcnt2, boff2, bcur2,
                                        off_ret, off_orig);
    bin_both<<<2 * NCHUNK, 256, 0, stream>>>(ret_idx, orig_idx, bcur1, bcur2, binned1, binned2);
    fill_both<<<NB_RET + NB_ORIG, 256, 0, stream>>>(binned1, boff1, off_ret, el1,
                                                    binned2, boff2, off_orig, el2);

    // ho = bf16(x_orig @ Wl1); xr = bf16(x_ret @ Wr1)   (one dispatch, 64-row tiles)
    gemm_lin<<<NBLK_HO + NBLK_XR, 256, 0, stream>>>(
        x_orig, x_ret, wtl1, wtr1, hoB, xrB);

    // r1s = bf16(relu(mean_agg(ho) + xr + bl1) * inv_s)   [200k x 128]
    gather_sage<<<(N_RET * 16) / 256, 256, 0, stream>>>(hoB, xrB, off_ret, el1, bl1, r1sB);

    // g = bf16(segment_sum(r1s))          [100k x 128]  (reuses hoB)
    gather_sum<<<(N_ORIG * 16) / 256, 256, 0, stream>>>(r1sB, off_orig, el2, hoB);

    // t = relu(g@Wg2*inv_d + bg2); out = t@Wout + bout   (fused, gather-free)
    gemm_t_out<<<(N_ORIG + 63) / 64, 256, 0, stream>>>(hoB, wtg2, wto, off_orig,
                                                       bg2, bout, out, N_ORIG);
}

// Round 12
// 206.961 us; speedup vs baseline: 1.1970x; 1.0529x over previous
//
#include <hip/hip_runtime.h>

#define N_RET  200000
#define N_ORIG 100000
#define N_EDGE 800000
#define NB_RET  ((N_RET  + 511) >> 9)   // 391 buckets of 512 nodes
#define NB_ORIG ((N_ORIG + 511) >> 9)   // 196
#define FILLB   (NB_RET + NB_ORIG)      // 587
#define ECHUNK  2048
#define NCHUNK  ((N_EDGE + ECHUNK - 1) / ECHUNK)  // 391 edge-chunk blocks
#define NBLK_HO ((N_ORIG + 63) / 64)    // 1563
#define NBLK_XR ((N_RET + 63) / 64)     // 3125

typedef __attribute__((ext_vector_type(8))) short bf16x8;   // 8 bf16 (4 VGPRs)
typedef __attribute__((ext_vector_type(4))) float f32x4;    // MFMA C/D

__device__ __forceinline__ ushort f2bf(float f) {
    union { float f; unsigned u; } v; v.f = f;
    unsigned r = v.u + 0x7FFFu + ((v.u >> 16) & 1u);   // RNE
    return (ushort)(r >> 16);
}
__device__ __forceinline__ float bf2f(ushort u) {
    union { unsigned u; float f; } v; v.u = ((unsigned)u) << 16;
    return v.f;
}
__device__ __forceinline__ int swz(int byteoff) {   // XOR swizzle for LDS tiles
    return byteoff ^ ((byteoff >> 4) & 0x70);
}

// ---- merged: weight transposes (blocks 0..223) + bucket histogram (blocks 224..614) ----
// bcnt zeroing is done by a preceding hipMemsetAsync (no intra-dispatch race).
__global__ __launch_bounds__(256) void prep_count(
    const float* __restrict__ Wl1, const float* __restrict__ Wr1,
    const float* __restrict__ Wg2, const float* __restrict__ Wout,
    ushort* __restrict__ wtl1, ushort* __restrict__ wtr1,
    ushort* __restrict__ wtg2, ushort* __restrict__ wto,
    const int* __restrict__ ridx, const int* __restrict__ cidx,
    int* __restrict__ bcnt1, int* __restrict__ bcnt2) {
    __shared__ int h1[512], h2[512];
    const int b = blockIdx.x, t = threadIdx.x;
    if (b < 224) {
        const float* W; ushort* WT; int base, nshift;
        if (b < 64)       { W = Wl1;  WT = wtl1; base = b;       nshift = 7; }
        else if (b < 128) { W = Wr1;  WT = wtr1; base = b - 64;  nshift = 7; }
        else if (b < 192) { W = Wg2;  WT = wtg2; base = b - 128; nshift = 7; }
        else              { W = Wout; WT = wto;  base = b - 192; nshift = 6; }
        int i = base * 256 + t;
        int k = i >> nshift, n = i & ((1 << nshift) - 1);
        WT[n * 128 + k] = f2bf(W[i]);   // K = 128 for all
        return;
    }
    const int c0 = (b - 224) * ECHUNK;
    for (int i = t; i < 512; i += 256) { h1[i] = 0; h2[i] = 0; }
    __syncthreads();
    for (int i = t; i < ECHUNK; i += 256) {
        int e = c0 + i;
        if (e < N_EDGE) {
            atomicAdd(&h1[ridx[e] >> 9], 1);
            atomicAdd(&h2[cidx[e] >> 9], 1);
        }
    }
    __syncthreads();
    for (int bb = t; bb < NB_RET; bb += 256)
        if (h1[bb]) atomicAdd(&bcnt1[bb], h1[bb]);
    for (int bb = t; bb < NB_ORIG; bb += 256)
        if (h2[bb]) atomicAdd(&bcnt2[bb], h2[bb]);
}

// ---------------- single-block scan of bucket counts -> bucket offsets + cursors ----------------
__global__ __launch_bounds__(256) void scan_buckets(const int* __restrict__ bcnt1,
                                                    int* __restrict__ boff1, int* __restrict__ bcur1,
                                                    const int* __restrict__ bcnt2,
                                                    int* __restrict__ boff2, int* __restrict__ bcur2,
                                                    int* __restrict__ off_ret,
                                                    int* __restrict__ off_orig) {
    __shared__ int sm[256];
    const int t = threadIdx.x;
    {
        int a0 = (2 * t     < NB_RET) ? bcnt1[2 * t]     : 0;
        int a1 = (2 * t + 1 < NB_RET) ? bcnt1[2 * t + 1] : 0;
        sm[t] = a0 + a1;
        __syncthreads();
        for (int d = 1; d < 256; d <<= 1) {
            int v = (t >= d) ? sm[t - d] : 0;
            __syncthreads(); sm[t] += v; __syncthreads();
        }
        int tb = t ? sm[t - 1] : 0;
        if (2 * t < NB_RET)     { boff1[2 * t]     = tb;      bcur1[2 * t]     = tb; }
        if (2 * t + 1 < NB_RET) { boff1[2 * t + 1] = tb + a0; bcur1[2 * t + 1] = tb + a0; }
        if (t == 0) { boff1[NB_RET] = N_EDGE; off_ret[N_RET] = N_EDGE; }
        __syncthreads();
    }
    {
        int a0 = (2 * t     < NB_ORIG) ? bcnt2[2 * t]     : 0;
        int a1 = (2 * t + 1 < NB_ORIG) ? bcnt2[2 * t + 1] : 0;
        sm[t] = a0 + a1;
        __syncthreads();
        for (int d = 1; d < 256; d <<= 1) {
            int v = (t >= d) ? sm[t - d] : 0;
            __syncthreads(); sm[t] += v; __syncthreads();
        }
        int tb = t ? sm[t - 1] : 0;
        if (2 * t < NB_ORIG)     { boff2[2 * t]     = tb;      bcur2[2 * t]     = tb; }
        if (2 * t + 1 < NB_ORIG) { boff2[2 * t + 1] = tb + a0; bcur2[2 * t + 1] = tb + a0; }
        if (t == 0) { boff2[NB_ORIG] = N_EDGE; off_orig[N_ORIG] = N_EDGE; }
    }
}

// ---------------- pass A (both dirs, 2048-edge chunks): bin by dst bucket ----------------
__global__ __launch_bounds__(256) void bin_both(const int* __restrict__ ridx,
                                                const int* __restrict__ cidx,
                                                int* __restrict__ bcur1, int* __restrict__ bcur2,
                                                int* __restrict__ binned1, int* __restrict__ binned2) {
    __shared__ int hist[512], base[512], lcur[512];
    const int t = threadIdx.x;
    const bool second = blockIdx.x >= NCHUNK;
    const int* dst = second ? cidx : ridx;
    const int* src = second ? ridx : cidx;
    int* bcur = second ? bcur2 : bcur1;
    int* binned = second ? binned2 : binned1;
    const int nbuckets = second ? NB_ORIG : NB_RET;
    const int c0 = (second ? blockIdx.x - NCHUNK : blockIdx.x) * ECHUNK;
    for (int i = t; i < 512; i += 256) { hist[i] = 0; lcur[i] = 0; }
    __syncthreads();
    for (int i = t; i < ECHUNK; i += 256) {
        int e = c0 + i;
        if (e < N_EDGE) atomicAdd(&hist[dst[e] >> 9], 1);
    }
    __syncthreads();
    for (int b = t; b < nbuckets; b += 256)
        base[b] = hist[b] > 0 ? atomicAdd(&bcur[b], hist[b]) : 0;
    __syncthreads();
    for (int i = t; i < ECHUNK; i += 256) {
        int e = c0 + i;
        if (e < N_EDGE) {
            int d = dst[e];
            int b = d >> 9;
            int r = atomicAdd(&lcur[b], 1);
            binned[base[b] + r] = ((d & 511) << 18) | src[e];
        }
    }
}

// ---- merged: per-bucket CSR fill (blocks 0..586) + linear GEMMs (blocks 587..5274) ----
// fill and gemm are mutually independent; fill blocks first so the latency-bound
// CSR fill hides under the BW-bound GEMM.
__global__ __launch_bounds__(256) void fill_gemm(
    const int* __restrict__ binned1, const int* __restrict__ boff1,
    int* __restrict__ off_ret, int* __restrict__ el1,
    const int* __restrict__ binned2, const int* __restrict__ boff2,
    int* __restrict__ off_orig, int* __restrict__ el2,
    const float* __restrict__ Ao, const float* __restrict__ Ar,
    const ushort* __restrict__ WTl, const ushort* __restrict__ WTr,
    ushort* __restrict__ hoB, ushort* __restrict__ xrB) {
    __shared__ char smem[32768];
    const int t = threadIdx.x;
    const int b = blockIdx.x;

    if (b < FILLB) {
        // ---- CSR fill path (3 KB of smem) ----
        int* hist = (int*)smem;            // 512 ints
        int* sm   = (int*)(smem + 2048);   // 256 ints
        const bool second = b >= NB_RET;
        const int bkt = second ? b - NB_RET : b;
        const int* binned = second ? binned2 : binned1;
        const int* boff = second ? boff2 : boff1;
        int* off = second ? off_orig : off_ret;
        int* el  = second ? el2 : el1;
        const int nnodes = second ? N_ORIG : N_RET;
        const int base = bkt << 9;
        const int nvalid = min(512, nnodes - base);
        const int s0 = boff[bkt], s1 = boff[bkt + 1];
        for (int i = t; i < 512; i += 256) hist[i] = 0;
        __syncthreads();
        for (int i = s0 + t; i < s1; i += 256)
            atomicAdd(&hist[binned[i] >> 18], 1);
        __syncthreads();
        int a0 = hist[2 * t], a1 = hist[2 * t + 1];
        sm[t] = a0 + a1;
        __syncthreads();
        for (int d = 1; d < 256; d <<= 1) {
            int v = (t >= d) ? sm[t - d] : 0;
            __syncthreads(); sm[t] += v; __syncthreads();
        }
        int tb = (t ? sm[t - 1] : 0) + s0;
        if (2 * t < nvalid)     off[base + 2 * t]     = tb;
        if (2 * t + 1 < nvalid) off[base + 2 * t + 1] = tb + a0;
        hist[2 * t] = tb;
        hist[2 * t + 1] = tb + a0;
        __syncthreads();
        for (int i = s0 + t; i < s1; i += 256) {
            int v = binned[i];
            int p = atomicAdd(&hist[v >> 18], 1);
            el[p] = v & 0x3FFFF;
        }
        return;
    }

    // ---- GEMM path: ho = bf16(x_orig@Wl1) / xr = bf16(x_ret@Wr1) ----
    ushort* Wlds = (ushort*)smem;          // 32 KB; reused as C-stage
    const int gb = b - FILLB;
    const bool second = gb >= NBLK_HO;
    const float* A = second ? Ar : Ao;
    const ushort* WT = second ? WTr : WTl;
    ushort* outp = second ? xrB : hoB;
    const int M = second ? N_RET : N_ORIG;
    const int i0 = (second ? gb - NBLK_HO : gb) * 64;

    #pragma unroll
    for (int it = 0; it < 8; ++it) {
        int idx = t + 256 * it;
        int n = idx >> 4, u = idx & 15;
        *(bf16x8*)&Wlds[swz(n * 256 + u * 16) >> 1] = *(const bf16x8*)&WT[idx * 8];
    }

    const int w = t >> 6, l = t & 63;
    const int r16 = l & 15, kg = l >> 4;
    const int arow = min(i0 + 16 * w + r16, M - 1);

    // A: issue all 8 float4 loads first (8-deep MLP), then convert
    float4 v[8];
    #pragma unroll
    for (int j = 0; j < 8; ++j)
        v[j] = *(const float4*)&A[(size_t)arow * 128 + (j >> 1) * 32 + kg * 8 + (j & 1) * 4];
    bf16x8 a[4];
    #pragma unroll
    for (int ks = 0; ks < 4; ++ks) {
        float4 v0 = v[2 * ks], v1 = v[2 * ks + 1];
        bf16x8 f;
        f[0] = (short)f2bf(v0.x); f[1] = (short)f2bf(v0.y);
        f[2] = (short)f2bf(v0.z); f[3] = (short)f2bf(v0.w);
        f[4] = (short)f2bf(v1.x); f[5] = (short)f2bf(v1.y);
        f[6] = (short)f2bf(v1.z); f[7] = (short)f2bf(v1.w);
        a[ks] = f;
    }
    __syncthreads();

    f32x4 acc[8];
    #pragma unroll
    for (int cf = 0; cf < 8; ++cf) acc[cf] = (f32x4){0.f, 0.f, 0.f, 0.f};
    #pragma unroll
    for (int cf = 0; cf < 8; ++cf) {
        int n = cf * 16 + r16;
        #pragma unroll
        for (int ks = 0; ks < 4; ++ks) {
            bf16x8 bb = *(const bf16x8*)&Wlds[swz(n * 256 + kg * 16 + ks * 64) >> 1];
            acc[cf] = __builtin_amdgcn_mfma_f32_16x16x32_bf16(a[ks], bb, acc[cf], 0, 0, 0);
        }
    }
    __syncthreads();   // Wlds fully consumed -> reuse as C staging

    #pragma unroll
    for (int r = 0; r < 4; ++r) {
        int row = 16 * w + 4 * kg + r;
        #pragma unroll
        for (int cf = 0; cf < 8; ++cf) {
            int ad = row * 256 + (cf * 16 + r16) * 2;
            Wlds[swz(ad) >> 1] = f2bf(acc[cf][r]);
        }
    }
    __syncthreads();

    const size_t obase = (size_t)i0 * 128;
    #pragma unroll
    for (int j = 0; j < 4; ++j) {
        int lb = j * 4096 + t * 16;
        bf16x8 val = *(const bf16x8*)&Wlds[swz(lb) >> 1];
        if (i0 + (lb >> 8) < M)
            *(bf16x8*)&outp[obase + (lb >> 1)] = val;
    }
}

// ---------------- gather + SAGE epilogue (unroll-2 edge loop) ----------------
__global__ void gather_sage(const ushort* __restrict__ ho, const ushort* __restrict__ xr,
                            const int* __restrict__ off, const int* __restrict__ slist,
                            const float* __restrict__ bl, ushort* __restrict__ r1s) {
    int gt = blockIdx.x * 256 + threadIdx.x;
    int node = gt >> 4;
    if (node >= N_RET) return;
    int o8 = gt & 15;
    int s = off[node], e = off[node + 1];
    float acc[8] = {0.f, 0.f, 0.f, 0.f, 0.f, 0.f, 0.f, 0.f};
    int i = s;
    for (; i + 2 <= e; i += 2) {
        int sn0 = slist[i], sn1 = slist[i + 1];
        bf16x8 v0 = *(const bf16x8*)&ho[(size_t)sn0 * 128 + o8 * 8];
        bf16x8 v1 = *(const bf16x8*)&ho[(size_t)sn1 * 128 + o8 * 8];
        #pragma unroll
        for (int j = 0; j < 8; ++j)
            acc[j] += bf2f((ushort)v0[j]) + bf2f((ushort)v1[j]);
    }
    if (i < e) {
        int sn = slist[i];
        bf16x8 v = *(const bf16x8*)&ho[(size_t)sn * 128 + o8 * 8];
        #pragma unroll
        for (int j = 0; j < 8; ++j) acc[j] += bf2f((ushort)v[j]);
    }
    int deg = e - s;
    float rinv = 1.0f / fmaxf((float)deg, 1.0f);
    float sinv = deg > 0 ? rsqrtf((float)deg) : 0.f;
    bf16x8 xv = *(const bf16x8*)&xr[(size_t)node * 128 + o8 * 8];
    bf16x8 ov;
    #pragma unroll
    for (int j = 0; j < 8; ++j) {
        float v = fmaxf(acc[j] * rinv + bf2f((ushort)xv[j]) + bl[o8 * 8 + j], 0.f) * sinv;
        ov[j] = (short)f2bf(v);
    }
    *(bf16x8*)&r1s[(size_t)node * 128 + o8 * 8] = ov;
}

// ---------------- gather sum (unroll-2 edge loop): g = bf16(sum of r1s rows) ----------------
__global__ void gather_sum(const ushort* __restrict__ src,
                           const int* __restrict__ off, const int* __restrict__ slist,
                           ushort* __restrict__ dst) {
    int gt = blockIdx.x * 256 + threadIdx.x;
    int node = gt >> 4;
    if (node >= N_ORIG) return;
    int o8 = gt & 15;
    int s = off[node], e = off[node + 1];
    float acc[8] = {0.f, 0.f, 0.f, 0.f, 0.f, 0.f, 0.f, 0.f};
    int i = s;
    for (; i + 2 <= e; i += 2) {
        int sn0 = slist[i], sn1 = slist[i + 1];
        bf16x8 v0 = *(const bf16x8*)&src[(size_t)sn0 * 128 + o8 * 8];
        bf16x8 v1 = *(const bf16x8*)&src[(size_t)sn1 * 128 + o8 * 8];
        #pragma unroll
        for (int j = 0; j < 8; ++j)
            acc[j] += bf2f((ushort)v0[j]) + bf2f((ushort)v1[j]);
    }
    if (i < e) {
        int sn = slist[i];
        bf16x8 v = *(const bf16x8*)&src[(size_t)sn * 128 + o8 * 8];
        #pragma unroll
        for (int j = 0; j < 8; ++j) acc[j] += bf2f((ushort)v[j]);
    }
    bf16x8 ov;
    #pragma unroll
    for (int j = 0; j < 8; ++j) ov[j] = (short)f2bf(acc[j]);
    *(bf16x8*)&dst[(size_t)node * 128 + o8 * 8] = ov;
}

// ---- fused double-GEMM (NO gather): t = relu(g@Wg2*inv_d + bg2); out = t@Wout + bout ----
__global__ __launch_bounds__(256) void gemm_t_out(
    const ushort* __restrict__ g, const ushort* __restrict__ WTg,
    const ushort* __restrict__ WTo, const int* __restrict__ off,
    const float* __restrict__ bg, const float* __restrict__ bo,
    float* __restrict__ out, int M) {
    __shared__ ushort Alds[64 * 128];    // 16 KB
    __shared__ ushort Wlds[128 * 128];   // 32 KB
    const int t = threadIdx.x;
    const int i0 = blockIdx.x * 64;

    #pragma unroll
    for (int it = 0; it < 8; ++it) {
        int idx = t + 256 * it;
        int n = idx >> 4, u = idx & 15;
        *(bf16x8*)&Wlds[swz(n * 256 + u * 16) >> 1] = *(const bf16x8*)&WTg[idx * 8];
    }
    #pragma unroll
    for (int it = 0; it < 4; ++it) {
        int idx = t + 256 * it;
        int row = idx >> 4, u = idx & 15;
        int gr = min(i0 + row, M - 1);
        bf16x8 v = *(const bf16x8*)&g[(size_t)gr * 128 + u * 8];
        *(bf16x8*)&Alds[swz(row * 256 + u * 16) >> 1] = v;
    }
    __syncthreads();

    const int w = t >> 6, l = t & 63;
    const int r16 = l & 15, kg = l >> 4;
    const int arow = 16 * w + r16;

    bf16x8 a[4];
    #pragma unroll
    for (int ks = 0; ks < 4; ++ks)
        a[ks] = *(const bf16x8*)&Alds[swz(arow * 256 + kg * 16 + ks * 64) >> 1];
    f32x4 acc[8];
    #pragma unroll
    for (int cf = 0; cf < 8; ++cf) acc[cf] = (f32x4){0.f, 0.f, 0.f, 0.f};
    #pragma unroll
    for (int cf = 0; cf < 8; ++cf) {
        int n = cf * 16 + r16;
        #pragma unroll
        for (int ks = 0; ks < 4; ++ks) {
            bf16x8 b = *(const bf16x8*)&Wlds[swz(n * 256 + kg * 16 + ks * 64) >> 1];
            acc[cf] = __builtin_amdgcn_mfma_f32_16x16x32_bf16(a[ks], b, acc[cf], 0, 0, 0);
        }
    }
    __syncthreads();

    #pragma unroll
    for (int r = 0; r < 4; ++r) {
        int row = 16 * w + 4 * kg + r;
        int grc = min(i0 + row, M - 1);
        int dg = off[grc + 1] - off[grc];
        float di = dg > 0 ? rsqrtf((float)dg) : 0.f;
        #pragma unroll
        for (int cf = 0; cf < 8; ++cf) {
            int col = cf * 16 + r16;
            float v = fmaxf(acc[cf][r] * di + bg[col], 0.f);
            Alds[swz(row * 256 + col * 2) >> 1] = f2bf(v);
        }
    }
    #pragma unroll
    for (int it = 0; it < 4; ++it) {
        int idx = t + 256 * it;
        int n = idx >> 4, u = idx & 15;
        *(bf16x8*)&Wlds[swz(n * 256 + u * 16) >> 1] = *(const bf16x8*)&WTo[idx * 8];
    }
    __syncthreads();

    bf16x8 a2[4];
    #pragma unroll
    for (int ks = 0; ks < 4; ++ks)
        a2[ks] = *(const bf16x8*)&Alds[swz(arow * 256 + kg * 16 + ks * 64) >> 1];
    f32x4 acc2[4];
    #pragma unroll
    for (int cf = 0; cf < 4; ++cf) acc2[cf] = (f32x4){0.f, 0.f, 0.f, 0.f};
    #pragma unroll
    for (int cf = 0; cf < 4; ++cf) {
        int n = cf * 16 + r16;
        #pragma unroll
        for (int ks = 0; ks < 4; ++ks) {
            bf16x8 b = *(const bf16x8*)&Wlds[swz(n * 256 + kg * 16 + ks * 64) >> 1];
            acc2[cf] = __builtin_amdgcn_mfma_f32_16x16x32_bf16(a2[ks], b, acc2[cf], 0, 0, 0);
        }
    }
    #pragma unroll
    for (int r = 0; r < 4; ++r) {
        int gr = i0 + 16 * w + 4 * kg + r;
        if (gr >= M) continue;
        #pragma unroll
        for (int cf = 0; cf < 4; ++cf) {
            int col = cf * 16 + r16;
            out[(size_t)gr * 64 + col] = acc2[cf][r] + bo[col];
        }
    }
}

extern "C" void kernel_launch(void* const* d_in, const int* in_sizes, int n_in,
                              void* d_out, int out_size, void* d_ws, size_t ws_size,
                              hipStream_t stream) {
    const float* x_ret    = (const float*)d_in[0];
    const float* x_orig   = (const float*)d_in[1];
    const int*   ret_idx  = (const int*)d_in[2];
    const int*   orig_idx = (const int*)d_in[3];
    const float* Wl1  = (const float*)d_in[6];
    const float* bl1  = (const float*)d_in[7];
    const float* Wr1  = (const float*)d_in[8];
    const float* Wg2  = (const float*)d_in[9];
    const float* bg2  = (const float*)d_in[10];
    const float* Wout = (const float*)d_in[14];
    const float* bout = (const float*)d_in[15];
    float* out = (float*)d_out;

    // workspace layout
    ushort* hoB  = (ushort*)d_ws;                       // 100k*128 bf16 (ho, later g)
    ushort* xrB  = hoB + (size_t)N_ORIG * 128;          // 200k*128 bf16
    ushort* r1sB = xrB + (size_t)N_RET * 128;           // 200k*128 bf16
    ushort* wtl1 = r1sB + (size_t)N_RET * 128;          // 16384
    ushort* wtr1 = wtl1 + 16384;                        // 16384
    ushort* wtg2 = wtr1 + 16384;                        // 16384
    ushort* wto  = wtg2 + 16384;                        // 8192
    int* off_ret  = (int*)(wto + 8192);                 // N_RET+1
    int* off_orig = off_ret + N_RET + 1;                // N_ORIG+1
    int* bcnt1    = off_orig + N_ORIG + 1;              // 512
    int* bcnt2    = bcnt1 + 512;                        // 512 (adjacent for one-pass zero)
    int* boff1    = bcnt2 + 512;                        // 512
    int* boff2    = boff1 + 512;                        // 512
    int* bcur1    = boff2 + 512;                        // 512
    int* bcur2    = bcur1 + 512;                        // 512
    int* el1      = bcur2 + 512;                        // N_EDGE (src=orig, grouped by ret)
    int* el2      = el1 + N_EDGE;                       // N_EDGE (src=ret, grouped by orig)
    int* binned1  = el2 + N_EDGE;                       // N_EDGE packed
    int* binned2  = binned1 + N_EDGE;                   // N_EDGE packed

    hipMemsetAsync(bcnt1, 0, 1024 * sizeof(int), stream);

    // weight transposes + bucket histogram (one dispatch, independent halves)
    prep_count<<<224 + NCHUNK, 256, 0, stream>>>(Wl1, Wr1, Wg2, Wout,
                                                 wtl1, wtr1, wtg2, wto,
                                                 ret_idx, orig_idx, bcnt1, bcnt2);

    scan_buckets<<<1, 256, 0, stream>>>(bcnt1, boff1, bcur1, bcnt2, boff2, bcur2,
                                        off_ret, off_orig);
    bin_both<<<2 * NCHUNK, 256, 0, stream>>>(ret_idx, orig_idx, bcur1, bcur2, binned1, binned2);

    // CSR fill + linear GEMMs (one dispatch; fill blocks first, gemm hides them)
    fill_gemm<<<FILLB + NBLK_HO + NBLK_XR, 256, 0, stream>>>(
        binned1, boff1, off_ret, el1, binned2, boff2, off_orig, el2,
        x_orig, x_ret, wtl1, wtr1, hoB, xrB);

    // r1s = bf16(relu(mean_agg(ho) + xr + bl1) * inv_s)   [200k x 128]
    gather_sage<<<(N_RET * 16) / 256, 256, 0, stream>>>(hoB, xrB, off_ret, el1, bl1, r1sB);

    // g = bf16(segment_sum(r1s))          [100k x 128]  (reuses hoB)
    gather_sum<<<(N_ORIG * 16) / 256, 256, 0, stream>>>(r1sB, off_orig, el2, hoB);

    // t = relu(g@Wg2*inv_d + bg2); out = t@Wout + bout   (fused, gather-free)
    gemm_t_out<<<(N_ORIG + 63) / 64, 256, 0, stream>>>(hoB, wtg2, wto, off_orig,
                                                       bg2, bout, out, N_ORIG);
}